// Round 7
// baseline (1018.813 us; speedup 1.0000x reference)
//
#include <hip/hip_runtime.h>

typedef unsigned short ushort;
typedef unsigned long long u64;
typedef __attribute__((ext_vector_type(8))) short short8;
typedef __attribute__((ext_vector_type(4))) float f32x4;

// Problem constants
constexpr int Bn = 8, Tn = 16, Nn = 512, Cn = 64, Hn = 64, En = 16384, Ln = 2;
constexpr int NC = Nn * Cn;           // 32768
constexpr int MROWS = Bn * Nn;        // 4096

// ---------------- workspace layout (in floats) ----------------
constexpr size_t OFF_DEG  = 0;
constexpr size_t OFF_DINV = 512;
constexpr size_t OFF_L1D  = 1024;                         // 512*512
constexpr size_t OFF_L2D  = OFF_L1D + 262144;
constexpr size_t OFF_WZR  = OFF_L2D + 262144;             // 2*384*128
constexpr size_t OFF_WHT  = OFF_WZR + 2*384*128;          // 2*384*64
constexpr size_t OFF_BZR  = OFF_WHT + 2*384*64;
constexpr size_t OFF_BHT  = OFF_BZR + 256;
constexpr size_t OFF_W1C  = OFF_BHT + 128;                // 8192
constexpr size_t OFF_T1X  = OFF_W1C + 8192;               // B*T*N*C
constexpr size_t OFF_T2X  = OFF_T1X + (size_t)Bn*Tn*NC;
constexpr size_t OFF_H    = OFF_T2X + (size_t)Bn*Tn*NC;   // B*N*H
constexpr size_t OFF_Z    = OFF_H   + (size_t)Bn*NC;
constexpr size_t OFF_HR   = OFF_Z   + (size_t)Bn*NC;
constexpr size_t OFF_SP   = OFF_HR  + (size_t)Bn*NC;      // sproj; W-frags alias this
constexpr size_t OFF_TP   = OFF_SP  + (size_t)MROWS*Hn;
constexpr size_t OFF_LFH  = OFF_TP  + (size_t)MROWS*Hn;   // L-frags bf16 hi/lo
constexpr size_t OFF_LFL  = OFF_LFH + 262144;
constexpr size_t OFF_HTH  = OFF_LFL + 262144;             // transposed bf16 h (hi only)
constexpr size_t OFF_HTL  = OFF_HTH + 131072;             // (unused)
constexpr size_t OFF_HRTH = OFF_HTL + 131072;
constexpr size_t OFF_HRTL = OFF_HRTH + 131072;            // (unused)
constexpr size_t OFF_BAR  = OFF_HRTL + 131072;            // 4096 ints of flag state
constexpr size_t OFF_END  = OFF_BAR + 4096;

__device__ __forceinline__ ushort f2bf(float f) {
    unsigned u = __float_as_uint(f);
    u = u + 0x7FFF + ((u >> 16) & 1);
    return (ushort)(u >> 16);
}
__device__ __forceinline__ float bf2f(ushort h) {
    return __uint_as_float(((unsigned)h) << 16);
}
// fragment-linear LDS layout for a 16x64 bf16 A-operand panel:
// value (m,k) lives at (k>>5)*512 + ((k>>3)&3)*128 + m*8 + (k&7)
__device__ __forceinline__ int fragaddr(int m, int k) {
    return ((k >> 5) << 9) + (((k >> 3) & 3) << 7) + (m << 3) + (k & 7);
}

#define MFMA16(a, b, c) __builtin_amdgcn_mfma_f32_16x16x32_bf16((a), (b), (c), 0, 0, 0)

// ---------------- setup kernels ----------------
__global__ void k_deg(const float* __restrict__ w, const int* __restrict__ src,
                      float* __restrict__ deg) {
    int e = blockIdx.x * 256 + threadIdx.x;
    if (e < En) atomicAdd(&deg[src[e]], w[e]);
}

__global__ void k_dinv(const float* __restrict__ deg, float* __restrict__ dinv) {
    int n = blockIdx.x * 256 + threadIdx.x;
    if (n < Nn) {
        float d = deg[n];
        dinv[n] = d > 0.f ? rsqrtf(fmaxf(d, 1e-12f)) : 0.f;
    }
}

__global__ void k_nwdense(const float* __restrict__ w, const int* __restrict__ src,
                          const int* __restrict__ dst, const float* __restrict__ dinv,
                          float* __restrict__ L1d) {
    int e = blockIdx.x * 256 + threadIdx.x;
    if (e < En) {
        int s = src[e], d = dst[e];
        float nw = -w[e] * dinv[s] * dinv[d];
        atomicAdd(&L1d[d * Nn + s], nw);
    }
}

// L2 = 2*(L1@L1) - I.  64 blocks x 1024 threads (4 waves/SIMD), 2x2 per thread.
__global__ __launch_bounds__(1024) void k_l2(const float* __restrict__ A,
                                             float* __restrict__ C) {
    __shared__ float As[64][33];
    __shared__ float Bs[32][65];
    int t = threadIdx.x;
    int i0 = (blockIdx.x >> 3) * 64;
    int j0 = (blockIdx.x & 7) * 64;
    int tx = t & 31, ty = t >> 5;          // 32x32 threads, each 2x2
    float acc[2][2] = {};
    int ar = t >> 4, ac = (t & 15) * 2;    // A stage: 64 rows x 32 k
    int br = t >> 5, bc = (t & 31) * 2;    // B stage: 32 k x 64 j
    for (int kc = 0; kc < 512; kc += 32) {
        float2 a2 = *(const float2*)&A[(size_t)(i0 + ar) * 512 + kc + ac];
        float2 b2 = *(const float2*)&A[(size_t)(kc + br) * 512 + j0 + bc];
        As[ar][ac] = a2.x; As[ar][ac + 1] = a2.y;
        Bs[br][bc] = b2.x; Bs[br][bc + 1] = b2.y;
        __syncthreads();
#pragma unroll 8
        for (int kk = 0; kk < 32; kk++) {
            float a0 = As[ty * 2][kk], a1 = As[ty * 2 + 1][kk];
            float b0 = Bs[kk][tx * 2], b1 = Bs[kk][tx * 2 + 1];
            acc[0][0] += a0 * b0; acc[0][1] += a0 * b1;
            acc[1][0] += a1 * b0; acc[1][1] += a1 * b1;
        }
        __syncthreads();
    }
#pragma unroll
    for (int r = 0; r < 2; r++)
#pragma unroll
        for (int c = 0; c < 2; c++) {
            int i = i0 + ty * 2 + r, j = j0 + tx * 2 + c;
            C[(size_t)i * 512 + j] = 2.f * acc[r][c] - (i == j ? 1.f : 0.f);
        }
}

// L1/L2 -> bf16 split A-fragments; idx = ((mat*32+rb)*16 + kc)*512 + lane*8 + j
__global__ void k_lfrag(const float* __restrict__ L1, const float* __restrict__ L2,
                        ushort* __restrict__ AfH, ushort* __restrict__ AfL) {
    int idx = blockIdx.x * 256 + threadIdx.x;   // 0..524287
    int j = idx & 7;
    int lane = (idx >> 3) & 63;
    int kc = (idx >> 9) & 15;
    int rb = (idx >> 13) & 31;
    int mat = idx >> 18;
    int row = rb * 16 + (lane & 15);
    int k = kc * 32 + (lane >> 4) * 8 + j;
    float v = (mat ? L2 : L1)[(size_t)row * 512 + k];
    ushort hi = f2bf(v);
    AfH[idx] = hi;
    AfL[idx] = f2bf(v - bf2f(hi));
}

// Wzr/Wht -> bf16 split B-fragments: idx = ((l*CT + ct)*12 + kc)*512 + lane*8 + j
__global__ void k_wfrag(const float* __restrict__ WzrC, const float* __restrict__ WhC,
                        ushort* __restrict__ WzFH, ushort* __restrict__ WzFL,
                        ushort* __restrict__ WhFH, ushort* __restrict__ WhFL) {
    int idx = blockIdx.x * 256 + threadIdx.x;
    if (idx < 98304) {
        int l = idx / 49152, off = idx % 49152;
        int tile = off >> 9, r = off & 511;
        int lane = r >> 3, j = r & 7;
        int ct = tile / 12, kc = tile % 12;
        int k = kc * 32 + (lane >> 4) * 8 + j;
        int n = ct * 16 + (lane & 15);
        float v = WzrC[(size_t)l * 49152 + k * 128 + n];
        ushort hi = f2bf(v);
        WzFH[idx] = hi;
        WzFL[idx] = f2bf(v - bf2f(hi));
    } else if (idx < 147456) {
        int t2 = idx - 98304;
        int l = t2 / 24576, off = t2 % 24576;
        int tile = off >> 9, r = off & 511;
        int lane = r >> 3, j = r & 7;
        int ct = tile / 12, kc = tile % 12;
        int k = kc * 32 + (lane >> 4) * 8 + j;
        int n = ct * 16 + (lane & 15);
        float v = WhC[(size_t)l * 24576 + k * 64 + n];
        ushort hi = f2bf(v);
        WhFH[t2] = hi;
        WhFL[t2] = f2bf(v - bf2f(hi));
    }
}

// ---------------- MFMA T1x/T2x: o1 = L1@x, o2 = L2@x per slice ----------------
__global__ __launch_bounds__(256) void k_lxm(
        const ushort* __restrict__ AfH, const ushort* __restrict__ AfL,
        const float* __restrict__ in, float* __restrict__ o1, float* __restrict__ o2) {
    __shared__ ushort Bh[2][2176];   // [buf][n*34 + k] (pad 34 halves)
    __shared__ ushort Bl[2][2176];
    int slice = blockIdx.x >> 3;
    int rg = blockIdx.x & 7;
    const float* xs = in + (size_t)slice * NC;
    int tid = threadIdx.x;
    int lane = tid & 63, wav = tid >> 6;
    int quad = lane >> 4, l15 = lane & 15;
    int sn = tid & 63, skq = tid >> 6;
    int rt = rg * 4 + wav;
    size_t abA = ((size_t)rt * 16) * 512 + lane * 8;        // L1 rows
    size_t abB = ((size_t)(32 + rt) * 16) * 512 + lane * 8; // L2 rows
    f32x4 accA[4], accB[4];
#pragma unroll
    for (int n = 0; n < 4; n++) {
        accA[n] = (f32x4){0.f, 0.f, 0.f, 0.f};
        accB[n] = (f32x4){0.f, 0.f, 0.f, 0.f};
    }
    {
        short8 hi8, lo8;
#pragma unroll
        for (int i = 0; i < 8; i++) {
            float v = xs[(size_t)(skq * 8 + i) * 64 + sn];
            ushort hv = f2bf(v);
            hi8[i] = (short)hv;
            lo8[i] = (short)f2bf(v - bf2f(hv));
        }
        *(short8*)&Bh[0][sn * 34 + skq * 8] = hi8;
        *(short8*)&Bl[0][sn * 34 + skq * 8] = lo8;
    }
    __syncthreads();
#pragma unroll
    for (int kc = 0; kc < 16; kc++) {
        const int cur = kc & 1;
        float sv[8];
        if (kc < 15) {
#pragma unroll
            for (int i = 0; i < 8; i++)
                sv[i] = xs[(size_t)((kc + 1) * 32 + skq * 8 + i) * 64 + sn];
        }
        size_t o = (size_t)kc * 512;
        short8 lah = *(const short8*)&AfH[abA + o];
        short8 lal = *(const short8*)&AfL[abA + o];
        short8 lbh = *(const short8*)&AfH[abB + o];
        short8 lbl = *(const short8*)&AfL[abB + o];
#pragma unroll
        for (int nt = 0; nt < 4; nt++) {
            short8 xh = *(const short8*)&Bh[cur][(nt * 16 + l15) * 34 + quad * 8];
            short8 xl = *(const short8*)&Bl[cur][(nt * 16 + l15) * 34 + quad * 8];
            accA[nt] = MFMA16(lah, xh, accA[nt]);
            accA[nt] = MFMA16(lah, xl, accA[nt]);
            accA[nt] = MFMA16(lal, xh, accA[nt]);
            accB[nt] = MFMA16(lbh, xh, accB[nt]);
            accB[nt] = MFMA16(lbh, xl, accB[nt]);
            accB[nt] = MFMA16(lbl, xh, accB[nt]);
        }
        if (kc < 15) {
            short8 hi8, lo8;
#pragma unroll
            for (int i = 0; i < 8; i++) {
                ushort hv = f2bf(sv[i]);
                hi8[i] = (short)hv;
                lo8[i] = (short)f2bf(sv[i] - bf2f(hv));
            }
            *(short8*)&Bh[cur ^ 1][sn * 34 + skq * 8] = hi8;
            *(short8*)&Bl[cur ^ 1][sn * 34 + skq * 8] = lo8;
        }
        __syncthreads();
    }
    float* os1 = o1 + (size_t)slice * NC;
    float* os2 = o2 + (size_t)slice * NC;
#pragma unroll
    for (int nt = 0; nt < 4; nt++)
#pragma unroll
        for (int reg = 0; reg < 4; reg++) {
            size_t row = (size_t)(rt * 16 + quad * 4 + reg);
            os1[row * 64 + nt * 16 + l15] = accA[nt][reg];
            os2[row * 64 + nt * 16 + l15] = accB[nt][reg];
        }
}

// repack weights.  A-column order: [h | x | T1x | T2x | U1 | U2] so that
// k-tiles 0..7 depend only on block-local data and 8..11 on the exchanged U1/U2.
__global__ void k_repack(const float* __restrict__ Wx, const float* __restrict__ bx,
                         const float* __restrict__ Wh, const float* __restrict__ bh,
                         const float* __restrict__ W1,
                         float* __restrict__ WzrC, float* __restrict__ WhC,
                         float* __restrict__ bzr, float* __restrict__ bht,
                         float* __restrict__ W1cat) {
    int idx = blockIdx.x * 256 + threadIdx.x;
    if (idx < 98304) {
        int l = idx / 49152, r = idx % 49152;
        int k = r / 128, j = r % 128;
        int g = j >> 6, hh = j & 63;
        int kc, c; const float* s;
        if (k < 64)       { kc = 0; c = k; s = Wh; }
        else if (k < 256) { kc = (k - 64) >> 6; c = (k - 64) & 63; s = Wx; }
        else              { kc = 1 + ((k - 256) >> 6); c = (k - 256) & 63; s = Wh; }
        WzrC[idx] = s[((((size_t)(l*3 + g))*3 + kc)*64 + c)*64 + hh];
    } else if (idx < 147456) {
        int tI = idx - 98304;
        int l = tI / 24576, r = tI % 24576;
        int k = r / 64, hh = r % 64;
        int kc, c; const float* s;
        if (k < 64)       { kc = 0; c = k; s = Wh; }
        else if (k < 256) { kc = (k - 64) >> 6; c = (k - 64) & 63; s = Wx; }
        else              { kc = 1 + ((k - 256) >> 6); c = (k - 256) & 63; s = Wh; }
        WhC[tI] = s[((((size_t)(l*3 + 2))*3 + kc)*64 + c)*64 + hh];
    } else if (idx < 147712) {
        int tI = idx - 147456;
        int l = tI >> 7, j = tI & 127;
        int g = j >> 6, hh = j & 63;
        bzr[tI] = bh[(l*3 + g)*64 + hh] + bx[(l*3 + g)*64 + hh];
    } else if (idx < 147840) {
        int tI = idx - 147712;
        int l = tI >> 6, hh = tI & 63;
        bht[tI] = bh[(l*3 + 2)*64 + hh] + bx[(l*3 + 2)*64 + hh];
    } else if (idx < 156032) {
        int tI = idx - 147840;
        int c = tI >> 7, j = tI & 127;
        W1cat[tI] = (j < 64) ? W1[c*64 + j] : W1[(64 + c)*64 + (j - 64)];
    }
}

// ================= persistent recurrence kernel =================
// NEW this round: each block owns the SAME rowblk for TWO independent b-groups
// (bA = g, bB = g+4).  The two recurrences interleave, so one group's flag
// propagation / detect latency is hidden under the other group's compute
// (round-6 counters: ~5.5 us/round of the 7.5 us round was exposed wait).
// The 64 KB L-panel in LDS is shared (L depends only on rowblk).
// 128 blocks x 256 threads, 152 KB LDS -> 1 block/CU, all co-resident.
// Exchange protocol unchanged: wide coherent vector ops (sc0 sc1) + epoch
// flags via relaxed agent atomics, NO fences.

__device__ __forceinline__ void wait_flags(int* gflags, int epoch) {
    if (threadIdx.x < 64) {
        bool done = threadIdx.x >= 32;
        while (!__all(done)) {
            if (!done)
                done = __hip_atomic_load(&gflags[threadIdx.x * 16],
                                         __ATOMIC_RELAXED,
                                         __HIP_MEMORY_SCOPE_AGENT) >= epoch;
            if (!__all(done)) __builtin_amdgcn_s_sleep(1);
        }
    }
    __syncthreads();
}

// drain both groups' payload stores, then publish both flags
__device__ __forceinline__ void arrive2(int* gfA, int* gfB, int rowblk, int epoch) {
    asm volatile("s_waitcnt vmcnt(0)" ::: "memory");
    __syncthreads();
    if (threadIdx.x == 0)
        __hip_atomic_store(&gfA[rowblk * 16], epoch,
                           __ATOMIC_RELAXED, __HIP_MEMORY_SCOPE_AGENT);
    else if (threadIdx.x == 64)
        __hip_atomic_store(&gfB[rowblk * 16], epoch,
                           __ATOMIC_RELAXED, __HIP_MEMORY_SCOPE_AGENT);
}

// write S (fp32 [16][64]) as bf16 transposed [64 cols][16 rows of this block].
// 128 threads x one 16B coherent vector store (sc0 sc1 = write to MALL).
__device__ __forceinline__ void store_T_pay(ushort* dstB, const float* S,
                                            int n0, int tid) {
    if (tid < 128) {
        int c = tid >> 1, half = tid & 1;   // col 0..63, node-octet 0..1
        short8 v;
#pragma unroll
        for (int j = 0; j < 8; j++)
            v[j] = (short)f2bf(S[(half * 8 + j) * 64 + c]);
        asm volatile("global_store_dwordx4 %0, %1, off sc0 sc1"
                     :: "v"(dstB + (size_t)c * 512 + n0 + half * 8), "v"(v)
                     : "memory");
    }
}

// stage segs 1,2,3 (x, T1x, T2x) — identical for l=0/1, so once per t
__device__ __forceinline__ void stage_xsegs(
        ushort* AH, ushort* AL, const float* __restrict__ x,
        const float* __restrict__ t1x, const float* __restrict__ t2x,
        size_t xoff, int tid) {
    int p = tid * 4;
    int m = p >> 6, kb = p & 63;
    int fa = fragaddr(m, kb);
    const float* srcs[3] = { x + xoff, t1x + xoff, t2x + xoff };
    const int sidx[3] = { 1, 2, 3 };
#pragma unroll
    for (int q = 0; q < 3; q++) {
        float4 v = *(const float4*)&srcs[q][(size_t)m * 64 + kb];
        float vv[4] = { v.x, v.y, v.z, v.w };
        int base = sidx[q] * 1024 + fa;
#pragma unroll
        for (int j = 0; j < 4; j++) {
            ushort hi = f2bf(vv[j]);
            AH[base + j] = hi;
            AL[base + j] = f2bf(vv[j] - bf2f(hi));
        }
    }
}

// stage seg 0 from an LDS-resident fp32 16x64 buffer (h or hr)
__device__ __forceinline__ void stage_h_lds(ushort* AH, ushort* AL,
                                            const float* hs, int tid) {
    int p = tid * 4;
    int m = p >> 6, kb = p & 63;
    int fa = fragaddr(m, kb);
#pragma unroll
    for (int j = 0; j < 4; j++) {
        float v = hs[m * 64 + kb + j];
        ushort hi = f2bf(v);
        AH[fa + j] = hi;
        AL[fa + j] = f2bf(v - bf2f(hi));
    }
}

// phase A: U1 = L1[rows,:]@src, U2 = L2[rows,:]@src via split-bf16 MFMA.
// A-side from LDS-cached panels; B-side (transposed h/hr, bf16 hi only):
// 16 wide coherent loads issued back-to-back, one vmcnt(0) drain, then MFMA.
// Writes U1 -> seg 4, U2 -> seg 5.
__device__ __forceinline__ void phase_A16_p(
        ushort* AH, ushort* AL, const ushort* LAH, const ushort* LAL,
        const ushort* __restrict__ sTh, int tid) {
    int lane = tid & 63, wav = tid >> 6;
    int quad = lane >> 4, l15 = lane & 15;
    int ab1 = lane * 8;
    int ab2 = 8192 + lane * 8;
    size_t bb = (size_t)(wav * 16 + l15) * 512 + quad * 8;
    f32x4 p1a = {0.f,0.f,0.f,0.f}, p1c = p1a, p2a = p1a, p2c = p1a;
    short8 bh[16];
#pragma unroll
    for (int s = 0; s < 16; s++) {
        asm volatile("global_load_dwordx4 %0, %1, off sc0 sc1"
                     : "=v"(bh[s]) : "v"(sTh + bb + (size_t)s * 32) : "memory");
    }
    asm volatile("s_waitcnt vmcnt(0)" ::: "memory");
    __builtin_amdgcn_sched_barrier(0);
    short8 a1h[2], a1l[2], a2h[2], a2l[2];
#pragma unroll
    for (int s = 0; s < 2; s++) {
        int o = s * 512;
        a1h[s] = *(const short8*)&LAH[ab1 + o];
        a1l[s] = *(const short8*)&LAL[ab1 + o];
        a2h[s] = *(const short8*)&LAH[ab2 + o];
        a2l[s] = *(const short8*)&LAL[ab2 + o];
    }
#pragma unroll
    for (int kc = 0; kc < 16; kc++) {
        int sa = kc & 1;
        p1a = MFMA16(a1h[sa], bh[kc], p1a);
        p1c = MFMA16(a1l[sa], bh[kc], p1c);
        p2a = MFMA16(a2h[sa], bh[kc], p2a);
        p2c = MFMA16(a2l[sa], bh[kc], p2c);
        if (kc + 2 < 16) {
            int o = (kc + 2) * 512;
            a1h[sa] = *(const short8*)&LAH[ab1 + o];
            a1l[sa] = *(const short8*)&LAL[ab1 + o];
            a2h[sa] = *(const short8*)&LAH[ab2 + o];
            a2l[sa] = *(const short8*)&LAL[ab2 + o];
        }
    }
    int colA = wav * 16 + l15;
#pragma unroll
    for (int reg = 0; reg < 4; reg++) {
        int row = quad * 4 + reg;
        float u1 = p1a[reg] + p1c[reg];
        float u2 = p2a[reg] + p2c[reg];
        ushort h1 = f2bf(u1), h2 = f2bf(u2);
        int fa1 = 4096 + fragaddr(row, colA);
        int fa2 = 5120 + fragaddr(row, colA);
        AH[fa1] = h1; AL[fa1] = f2bf(u1 - bf2f(h1));
        AH[fa2] = h2; AL[fa2] = f2bf(u2 - bf2f(h2));
    }
}

// phase B1 pre: kt 0..7 (segs h,x,T1x,T2x) — runs BEFORE the payload wait.
__device__ __forceinline__ void phase_B1_pre(
        const ushort* AH, const ushort* AL,
        const ushort* __restrict__ WFH, const ushort* __restrict__ WFL,
        f32x4* q, int tid) {
    int lane = tid & 63, wav = tid >> 6;
    int quad = lane >> 4, l15 = lane & 15;
    int abase = quad * 128 + l15 * 8;
    size_t w0 = ((size_t)wav * 12) * 512 + lane * 8;
    size_t w1 = ((size_t)(4 + wav) * 12) * 512 + lane * 8;
    short8 ah[2], al[2], w0h[4], w0l[4], w1h[4], w1l[4];
#pragma unroll
    for (int s = 0; s < 2; s++) {
        ah[s] = *(const short8*)&AH[abase + s * 512];
        al[s] = *(const short8*)&AL[abase + s * 512];
    }
#pragma unroll
    for (int s = 0; s < 4; s++) {
        size_t o = (size_t)s * 512;
        w0h[s] = *(const short8*)&WFH[w0 + o];
        w0l[s] = *(const short8*)&WFL[w0 + o];
        w1h[s] = *(const short8*)&WFH[w1 + o];
        w1l[s] = *(const short8*)&WFL[w1 + o];
    }
#pragma unroll
    for (int kt = 0; kt < 8; kt++) {
        int sa = kt & 1, sw = kt & 3;
        q[0] = MFMA16(ah[sa], w0h[sw], q[0]);
        q[1] = MFMA16(ah[sa], w0l[sw], q[1]);
        q[2] = MFMA16(al[sa], w0h[sw], q[2]);
        q[3] = MFMA16(ah[sa], w1h[sw], q[3]);
        q[4] = MFMA16(ah[sa], w1l[sw], q[4]);
        q[5] = MFMA16(al[sa], w1h[sw], q[5]);
        if (kt + 2 < 8) {
            ah[sa] = *(const short8*)&AH[abase + (kt + 2) * 512];
            al[sa] = *(const short8*)&AL[abase + (kt + 2) * 512];
        }
        if (kt + 4 < 8) {
            size_t o = (size_t)(kt + 4) * 512;
            w0h[sw] = *(const short8*)&WFH[w0 + o];
            w0l[sw] = *(const short8*)&WFL[w0 + o];
            w1h[sw] = *(const short8*)&WFH[w1 + o];
            w1l[sw] = *(const short8*)&WFL[w1 + o];
        }
    }
}

// phase B1 post: kt 8..11 (U1,U2) — after phase A; writes PRED.
__device__ __forceinline__ void phase_B1_post(
        const ushort* AH, const ushort* AL,
        const ushort* __restrict__ WFH, const ushort* __restrict__ WFL,
        f32x4* q, float* PRED, int tid) {
    int lane = tid & 63, wav = tid >> 6;
    int quad = lane >> 4, l15 = lane & 15;
    int abase = quad * 128 + l15 * 8;
    size_t w0 = ((size_t)wav * 12) * 512 + lane * 8;
    size_t w1 = ((size_t)(4 + wav) * 12) * 512 + lane * 8;
    short8 ah[4], al[4], w0h[4], w0l[4], w1h[4], w1l[4];
#pragma unroll
    for (int s = 0; s < 4; s++) {
        int o = (8 + s) * 512;
        ah[s] = *(const short8*)&AH[abase + o];
        al[s] = *(const short8*)&AL[abase + o];
        size_t wo = (size_t)(8 + s) * 512;
        w0h[s] = *(const short8*)&WFH[w0 + wo];
        w0l[s] = *(const short8*)&WFL[w0 + wo];
        w1h[s] = *(const short8*)&WFH[w1 + wo];
        w1l[s] = *(const short8*)&WFL[w1 + wo];
    }
#pragma unroll
    for (int kt = 0; kt < 4; kt++) {
        q[0] = MFMA16(ah[kt], w0h[kt], q[0]);
        q[1] = MFMA16(ah[kt], w0l[kt], q[1]);
        q[2] = MFMA16(al[kt], w0h[kt], q[2]);
        q[3] = MFMA16(ah[kt], w1h[kt], q[3]);
        q[4] = MFMA16(ah[kt], w1l[kt], q[4]);
        q[5] = MFMA16(al[kt], w1h[kt], q[5]);
    }
#pragma unroll
    for (int reg = 0; reg < 4; reg++) {
        int row = quad * 4 + reg;
        PRED[row * 128 + wav * 16 + l15] = q[0][reg] + q[1][reg] + q[2][reg];
        PRED[row * 128 + 64 + wav * 16 + l15] = q[3][reg] + q[4][reg] + q[5][reg];
    }
}

// phase B2 pre/post: ht[16][64] = A[16][384] @ Wht
__device__ __forceinline__ void phase_B2_pre(
        const ushort* AH, const ushort* AL,
        const ushort* __restrict__ WFH, const ushort* __restrict__ WFL,
        f32x4* q, int tid) {
    int lane = tid & 63, wav = tid >> 6;
    int quad = lane >> 4, l15 = lane & 15;
    int abase = quad * 128 + l15 * 8;
    size_t w0 = ((size_t)wav * 12) * 512 + lane * 8;
    short8 ah[2], al[2], wh[4], wl[4];
#pragma unroll
    for (int s = 0; s < 2; s++) {
        ah[s] = *(const short8*)&AH[abase + s * 512];
        al[s] = *(const short8*)&AL[abase + s * 512];
    }
#pragma unroll
    for (int s = 0; s < 4; s++) {
        wh[s] = *(const short8*)&WFH[w0 + (size_t)s * 512];
        wl[s] = *(const short8*)&WFL[w0 + (size_t)s * 512];
    }
#pragma unroll
    for (int kt = 0; kt < 8; kt++) {
        int sa = kt & 1, sw = kt & 3;
        q[0] = MFMA16(ah[sa], wh[sw], q[0]);
        q[1] = MFMA16(ah[sa], wl[sw], q[1]);
        q[2] = MFMA16(al[sa], wh[sw], q[2]);
        if (kt + 2 < 8) {
            ah[sa] = *(const short8*)&AH[abase + (kt + 2) * 512];
            al[sa] = *(const short8*)&AL[abase + (kt + 2) * 512];
        }
        if (kt + 4 < 8) {
            size_t o = (size_t)(kt + 4) * 512;
            wh[sw] = *(const short8*)&WFH[w0 + o];
            wl[sw] = *(const short8*)&WFL[w0 + o];
        }
    }
}

__device__ __forceinline__ void phase_B2_post(
        const ushort* AH, const ushort* AL,
        const ushort* __restrict__ WFH, const ushort* __restrict__ WFL,
        f32x4* q, float* PRED, int tid) {
    int lane = tid & 63, wav = tid >> 6;
    int quad = lane >> 4, l15 = lane & 15;
    int abase = quad * 128 + l15 * 8;
    size_t w0 = ((size_t)wav * 12) * 512 + lane * 8;
    short8 ah[4], al[4], wh[4], wl[4];
#pragma unroll
    for (int s = 0; s < 4; s++) {
        int o = (8 + s) * 512;
        ah[s] = *(const short8*)&AH[abase + o];
        al[s] = *(const short8*)&AL[abase + o];
        size_t wo = (size_t)(8 + s) * 512;
        wh[s] = *(const short8*)&WFH[w0 + wo];
        wl[s] = *(const short8*)&WFL[w0 + wo];
    }
#pragma unroll
    for (int kt = 0; kt < 4; kt++) {
        q[0] = MFMA16(ah[kt], wh[kt], q[0]);
        q[1] = MFMA16(ah[kt], wl[kt], q[1]);
        q[2] = MFMA16(al[kt], wh[kt], q[2]);
    }
#pragma unroll
    for (int reg = 0; reg < 4; reg++)
        PRED[(quad * 4 + reg) * 64 + wav * 16 + l15] = q[0][reg] + q[1][reg] + q[2][reg];
}

__global__ __launch_bounds__(256, 1) void k_recur(
        const float* __restrict__ x, const float* __restrict__ t1x,
        const float* __restrict__ t2x,
        const ushort* __restrict__ AfH, const ushort* __restrict__ AfL,
        const ushort* __restrict__ WzFH, const ushort* __restrict__ WzFL,
        const ushort* __restrict__ WhFH, const ushort* __restrict__ WhFL,
        const float* __restrict__ bzr, const float* __restrict__ bht,
        float* __restrict__ h, ushort* __restrict__ hTh,
        ushort* __restrict__ hrTh, int* __restrict__ bar) {
    // per-group A-panels / outputs (groups A and B), shared L-panels
    __shared__ __attribute__((aligned(16))) ushort AH0[6144], AL0[6144];  // 24 KB
    __shared__ __attribute__((aligned(16))) ushort AH1[6144], AL1[6144];  // 24 KB
    __shared__ __attribute__((aligned(16))) float  PRED0[2048], PRED1[2048]; // 16 KB
    __shared__ __attribute__((aligned(16))) float  HS0[1024], ZS0[1024], HRS0[1024]; // 12 KB
    __shared__ __attribute__((aligned(16))) float  HS1[1024], ZS1[1024], HRS1[1024]; // 12 KB
    __shared__ __attribute__((aligned(16))) ushort LAH[16384], LAL[16384]; // 64 KB
    int tid = threadIdx.x;
    int g = blockIdx.x >> 5;         // 0..3
    int bA = g, bB = g + 4;
    int rowblk = blockIdx.x & 31;
    int n0 = rowblk * 16;
    int* gfA = bar + bA * 512;       // 32 slots x 16 ints (64 B apart)
    int* gfB = bar + bB * 512;

    // one-time: this rowblk's L panels -> LDS (shared by both groups); h = 0
    for (int i = tid; i < 1024; i += 256) {
        *(short8*)&LAH[i * 8] = *(const short8*)&AfH[(size_t)rowblk * 8192 + i * 8];
        *(short8*)&LAL[i * 8] = *(const short8*)&AfL[(size_t)rowblk * 8192 + i * 8];
        *(short8*)&LAH[8192 + i * 8] = *(const short8*)&AfH[(size_t)(32 + rowblk) * 8192 + i * 8];
        *(short8*)&LAL[8192 + i * 8] = *(const short8*)&AfL[(size_t)(32 + rowblk) * 8192 + i * 8];
    }
    for (int i = tid; i < 1024; i += 256) { HS0[i] = 0.f; HS1[i] = 0.f; }
    __syncthreads();

    ushort* hThA  = hTh  + (size_t)bA * 32768;
    ushort* hrThA = hrTh + (size_t)bA * 32768;
    ushort* hThB_ = hTh  + (size_t)bB * 32768;
    ushort* hrThB_= hrTh + (size_t)bB * 32768;
    int ep = 0;
#pragma unroll 1
    for (int t = 0; t < Tn; t++) {
        size_t xoffA = ((size_t)(bA * Tn + t) * Nn + n0) * 64;
        size_t xoffB = ((size_t)(bB * Tn + t) * Nn + n0) * 64;
        stage_xsegs(AH0, AL0, x, t1x, t2x, xoffA, tid);   // segs 1..3 group A
        stage_xsegs(AH1, AL1, x, t1x, t2x, xoffB, tid);   // segs 1..3 group B
#pragma unroll 1
        for (int l = 0; l < Ln; l++) {
            const ushort* WzH = WzFH + (size_t)l * 49152;
            const ushort* WzL = WzFL + (size_t)l * 49152;
            const ushort* WtH = WhFH + (size_t)l * 24576;
            const ushort* WtL = WhFL + (size_t)l * 24576;
            const float* bz = bzr + l * 128;
            const float* bt = bht + l * 64;
            // ======== half-cell 1 (both groups): z,r gates; hr = h*r ========
            stage_h_lds(AH0, AL0, HS0, tid);
            stage_h_lds(AH1, AL1, HS1, tid);
            __syncthreads();
            f32x4 qA[6], qB[6];
#pragma unroll
            for (int i = 0; i < 6; i++) { qA[i] = (f32x4){0.f,0.f,0.f,0.f}; qB[i] = qA[i]; }
            phase_B1_pre(AH0, AL0, WzH, WzL, qA, tid);    // local kt 0..7, A
            phase_B1_pre(AH1, AL1, WzH, WzL, qB, tid);    // local kt 0..7, B
            wait_flags(gfA, ep);                          // covered by pres
            phase_A16_p(AH0, AL0, LAH, LAL, hThA, tid);   // payload A -> U1,U2
            wait_flags(gfB, ep);                          // covered by phase_A(A)
            phase_A16_p(AH1, AL1, LAH, LAL, hThB_, tid);  // payload B
            __syncthreads();
            phase_B1_post(AH0, AL0, WzH, WzL, qA, PRED0, tid);
            phase_B1_post(AH1, AL1, WzH, WzL, qB, PRED1, tid);
            __syncthreads();
            for (int i = tid; i < 2048; i += 256) {
                int r = i >> 7, c = i & 127;
                float v = PRED0[i] + bz[c];
                float s = 1.f / (1.f + __expf(-v));
                if (c < 64) ZS0[r * 64 + c] = s;
                else { int c2 = c - 64; HRS0[r * 64 + c2] = HS0[r * 64 + c2] * s; }
            }
            for (int i = tid; i < 2048; i += 256) {
                int r = i >> 7, c = i & 127;
                float v = PRED1[i] + bz[c];
                float s = 1.f / (1.f + __expf(-v));
                if (c < 64) ZS1[r * 64 + c] = s;
                else { int c2 = c - 64; HRS1[r * 64 + c2] = HS1[r * 64 + c2] * s; }
            }
            __syncthreads();
            store_T_pay(hrThA, HRS0, n0, tid);
            store_T_pay(hrThB_, HRS1, n0, tid);
            arrive2(gfA, gfB, rowblk, ep + 1);
            ep++;
            // ======== half-cell 2 (both groups): ht; h = z*h + (1-z)*ht ========
            stage_h_lds(AH0, AL0, HRS0, tid);
            stage_h_lds(AH1, AL1, HRS1, tid);
            __syncthreads();
            f32x4 rA[3], rB[3];
#pragma unroll
            for (int i = 0; i < 3; i++) { rA[i] = (f32x4){0.f,0.f,0.f,0.f}; rB[i] = rA[i]; }
            phase_B2_pre(AH0, AL0, WtH, WtL, rA, tid);
            phase_B2_pre(AH1, AL1, WtH, WtL, rB, tid);
            wait_flags(gfA, ep);
            phase_A16_p(AH0, AL0, LAH, LAL, hrThA, tid);
            wait_flags(gfB, ep);
            phase_A16_p(AH1, AL1, LAH, LAL, hrThB_, tid);
            __syncthreads();
            phase_B2_post(AH0, AL0, WtH, WtL, rA, PRED0, tid);
            phase_B2_post(AH1, AL1, WtH, WtL, rB, PRED1, tid);
            __syncthreads();
            for (int i = tid; i < 1024; i += 256) {
                int c = i & 63;
                float v = PRED0[i] + bt[c];
                float av = fabsf(v);
                float e2 = __expf(-2.f * av);
                float m = (1.f - e2) / (1.f + e2);
                float htv = v < 0.f ? -m : m;
                float zz = ZS0[i], hold = HS0[i];
                float hn = zz * hold + (1.f - zz) * htv;
                HS0[i] = hn;
                if (t == Tn - 1 && l == Ln - 1)
                    h[((size_t)(bA * Nn + n0 + (i >> 6))) * 64 + c] = hn;
            }
            for (int i = tid; i < 1024; i += 256) {
                int c = i & 63;
                float v = PRED1[i] + bt[c];
                float av = fabsf(v);
                float e2 = __expf(-2.f * av);
                float m = (1.f - e2) / (1.f + e2);
                float htv = v < 0.f ? -m : m;
                float zz = ZS1[i], hold = HS1[i];
                float hn = zz * hold + (1.f - zz) * htv;
                HS1[i] = hn;
                if (t == Tn - 1 && l == Ln - 1)
                    h[((size_t)(bB * Nn + n0 + (i >> 6))) * 64 + c] = hn;
            }
            __syncthreads();
            store_T_pay(hThA, HS0, n0, tid);
            store_T_pay(hThB_, HS1, n0, tid);
            arrive2(gfA, gfB, rowblk, ep + 1);
            ep++;
        }
    }
}

// ---------------- projections ----------------
__global__ __launch_bounds__(256) void k_proj(
        const float* __restrict__ h, const float* __restrict__ W1cat,
        const float* __restrict__ b1,
        float* __restrict__ sproj, float* __restrict__ tproj) {
    __shared__ float As[16][33];
    __shared__ float Ws[16 * 128];
    int tid = threadIdx.x;
    int row0 = blockIdx.x * 32;
    const float* hp = h + (size_t)row0 * 64;
    float acc[2][8] = {};
    int tx = tid & 15, ty = tid >> 4;
    int lr = tid >> 3;
    int lk = (tid & 7) * 2;
    int wk = tid >> 4;
    int wc = (tid & 15) * 8;
    for (int kt = 0; kt < 4; kt++) {
        int c0 = kt * 16;
        float2 a2 = *(const float2*)&hp[lr * 64 + c0 + lk];
        const float4* wsrc = (const float4*)&W1cat[(size_t)(kt * 16 + wk) * 128 + wc];
        float4 w0 = wsrc[0], w1 = wsrc[1];
        As[lk][lr] = a2.x;
        As[lk + 1][lr] = a2.y;
        *(float4*)&Ws[wk * 128 + wc] = w0;
        *(float4*)&Ws[wk * 128 + wc + 4] = w1;
        __syncthreads();
#pragma unroll
        for (int kk = 0; kk < 16; kk++) {
            float a0 = As[kk][ty * 2 + 0];
            float a1 = As[kk][ty * 2 + 1];
            float4 p0 = *(const float4*)&Ws[kk * 128 + tx * 8];
            float4 p1 = *(const float4*)&Ws[kk * 128 + tx * 8 + 4];
            float w[8] = { p0.x, p0.y, p0.z, p0.w, p1.x, p1.y, p1.z, p1.w };
#pragma unroll
            for (int cc = 0; cc < 8; cc++) {
                acc[0][cc] += a0 * w[cc];
                acc[1][cc] += a1 * w[cc];
            }
        }
        __syncthreads();
    }
#pragma unroll
    for (int rr = 0; rr < 2; rr++) {
        int row = row0 + ty * 2 + rr;
#pragma unroll
        for (int cc = 0; cc < 8; cc++) {
            int col = tx * 8 + cc;
            float v = acc[rr][cc];
            if (col < 64) sproj[(size_t)row * 64 + col] = v + b1[col];
            else tproj[(size_t)row * 64 + (col - 64)] = v;
        }
    }
}

// ---------------- logits ----------------
__global__ __launch_bounds__(256) void k_logits(
        const float* __restrict__ sproj, const float* __restrict__ tproj,
        const float* __restrict__ W2, const float* __restrict__ b2,
        float* __restrict__ out) {
    __shared__ float sp[32 * 64];
    __shared__ float tp[64 * 65];
    __shared__ float w2s[64];
    int tid = threadIdx.x;
    int bb = blockIdx.x >> 7;
    int st = (blockIdx.x >> 3) & 15;
    int tt = blockIdx.x & 7;
    const float* spg = sproj + ((size_t)bb * Nn + st * 32) * 64;
    const float* tpg = tproj + ((size_t)bb * Nn + tt * 64) * 64;
    for (int i = tid; i < 2048; i += 256) sp[i] = spg[i];
    for (int i = tid; i < 4096; i += 256) {
        int tl = i >> 6, hh = i & 63;
        tp[tl * 65 + hh] = tpg[i];
    }
    if (tid < 64) w2s[tid] = W2[tid];
    __syncthreads();
    float bias = *b2;
    int tl = tid & 63, sg = tid >> 6;
    for (int si = 0; si < 8; si++) {
        int s = sg * 8 + si;
        float acc = bias;
#pragma unroll 8
        for (int hh = 0; hh < 64; hh++) {
            float v = sp[s * 64 + hh] + tp[tl * 65 + hh];
            acc += fmaxf(v, 0.f) * w2s[hh];
        }
        out[(size_t)bb * Nn * Nn + (size_t)(st * 32 + s) * Nn + tt * 64 + tl] = acc;
    }
}

// ---------------- host ----------------
extern "C" void kernel_launch(void* const* d_in, const int* in_sizes, int n_in,
                              void* d_out, int out_size, void* d_ws, size_t ws_size,
                              hipStream_t stream) {
    const float* x  = (const float*)d_in[0];
    const float* ew = (const float*)d_in[1];
    const float* Wx = (const float*)d_in[2];
    const float* bx = (const float*)d_in[3];
    const float* Wh = (const float*)d_in[4];
    const float* bh = (const float*)d_in[5];
    const float* W1 = (const float*)d_in[6];
    const float* b1 = (const float*)d_in[7];
    const float* W2 = (const float*)d_in[8];
    const float* b2 = (const float*)d_in[9];
    const int* ei   = (const int*)d_in[10];
    const int* esrc = ei;
    const int* edst = ei + En;

    float* ws = (float*)d_ws;
    float* deg   = ws + OFF_DEG;
    float* dinv  = ws + OFF_DINV;
    float* L1d   = ws + OFF_L1D;
    float* L2d   = ws + OFF_L2D;
    float* WzrC  = ws + OFF_WZR;
    float* WhC   = ws + OFF_WHT;
    float* bzr   = ws + OFF_BZR;
    float* bht   = ws + OFF_BHT;
    float* W1cat = ws + OFF_W1C;
    float* T1x   = ws + OFF_T1X;
    float* T2x   = ws + OFF_T2X;
    float* h     = ws + OFF_H;
    float* sproj = ws + OFF_SP;
    float* tproj = ws + OFF_TP;
    ushort* AfH  = (ushort*)(ws + OFF_LFH);
    ushort* AfL  = (ushort*)(ws + OFF_LFL);
    ushort* hTh  = (ushort*)(ws + OFF_HTH);
    ushort* hrTh = (ushort*)(ws + OFF_HRTH);
    int* bar     = (int*)(ws + OFF_BAR);
    // W-fragments alias the sproj region (dead until k_proj, which runs after recurrence)
    ushort* WzFH = (ushort*)(ws + OFF_SP);
    ushort* WzFL = WzFH + 98304;
    ushort* WhFH = WzFL + 98304;
    ushort* WhFL = WhFH + 49152;
    float* out   = (float*)d_out;

    hipMemsetAsync(deg, 0, 512 * sizeof(float), stream);
    hipMemsetAsync(L1d, 0, (size_t)Nn * Nn * sizeof(float), stream);
    hipMemsetAsync(h, 0, (size_t)Bn * NC * sizeof(float), stream);
    hipMemsetAsync(hTh, 0, 262144 * sizeof(ushort), stream);
    hipMemsetAsync(bar, 0, 4096 * sizeof(int), stream);

    k_deg<<<64, 256, 0, stream>>>(ew, esrc, deg);
    k_dinv<<<2, 256, 0, stream>>>(deg, dinv);
    k_nwdense<<<64, 256, 0, stream>>>(ew, esrc, edst, dinv, L1d);
    k_l2<<<64, 1024, 0, stream>>>(L1d, L2d);
    k_lfrag<<<2048, 256, 0, stream>>>(L1d, L2d, AfH, AfL);
    k_repack<<<(156032 + 255) / 256, 256, 0, stream>>>(Wx, bx, Wh, bh, W1,
                                                       WzrC, WhC, bzr, bht, W1cat);
    k_wfrag<<<(147456 + 255) / 256, 256, 0, stream>>>(WzrC, WhC, WzFH, WzFL, WhFH, WhFL);

    // T1x/T2x via MFMA — 1024 blocks (4 waves/SIMD)
    k_lxm<<<1024, 256, 0, stream>>>(AfH, AfL, x, T1x, T2x);

    // full recurrence: 128 persistent blocks x 256 threads, each block runs
    // TWO independent b-groups (bA = g, bB = g+4) interleaved to hide the
    // exchange latency under the other group's compute.
    k_recur<<<128, 256, 0, stream>>>(x, T1x, T2x, AfH, AfL, WzFH, WzFL,
                                     WhFH, WhFL, bzr, bht, h, hTh, hrTh, bar);

    k_proj<<<128, 256, 0, stream>>>(h, W1cat, b1, sproj, tproj);
    k_logits<<<Bn * 16 * 8, 256, 0, stream>>>(sproj, tproj, W2, b2, out);
}

// Round 10
// 680.683 us; speedup vs baseline: 1.4968x; 1.4968x over previous
//
#include <hip/hip_runtime.h>

typedef unsigned short ushort;
typedef unsigned long long u64;
typedef __attribute__((ext_vector_type(8))) short short8;
typedef __attribute__((ext_vector_type(4))) float f32x4;

// Problem constants
constexpr int Bn = 8, Tn = 16, Nn = 512, Cn = 64, Hn = 64, En = 16384, Ln = 2;
constexpr int NC = Nn * Cn;           // 32768
constexpr int MROWS = Bn * Nn;        // 4096

// ---------------- workspace layout (in floats) ----------------
constexpr size_t OFF_DEG  = 0;
constexpr size_t OFF_DINV = 512;
constexpr size_t OFF_L1D  = 1024;                         // 512*512
constexpr size_t OFF_L2D  = OFF_L1D + 262144;
constexpr size_t OFF_WZR  = OFF_L2D + 262144;             // 2*384*128
constexpr size_t OFF_WHT  = OFF_WZR + 2*384*128;          // 2*384*64
constexpr size_t OFF_BZR  = OFF_WHT + 2*384*64;
constexpr size_t OFF_BHT  = OFF_BZR + 256;
constexpr size_t OFF_W1C  = OFF_BHT + 128;                // 8192
constexpr size_t OFF_T1X  = OFF_W1C + 8192;               // B*T*N*C
constexpr size_t OFF_T2X  = OFF_T1X + (size_t)Bn*Tn*NC;
constexpr size_t OFF_H    = OFF_T2X + (size_t)Bn*Tn*NC;   // B*N*H
constexpr size_t OFF_Z    = OFF_H   + (size_t)Bn*NC;
constexpr size_t OFF_HR   = OFF_Z   + (size_t)Bn*NC;
constexpr size_t OFF_SP   = OFF_HR  + (size_t)Bn*NC;      // sproj; W-frags alias this
constexpr size_t OFF_TP   = OFF_SP  + (size_t)MROWS*Hn;
constexpr size_t OFF_LFH  = OFF_TP  + (size_t)MROWS*Hn;   // L-frags bf16 hi/lo
constexpr size_t OFF_LFL  = OFF_LFH + 262144;
constexpr size_t OFF_HTH  = OFF_LFL + 262144;             // transposed bf16 h (hi only)
constexpr size_t OFF_HTL  = OFF_HTH + 131072;             // (unused)
constexpr size_t OFF_HRTH = OFF_HTL + 131072;
constexpr size_t OFF_HRTL = OFF_HRTH + 131072;            // (unused)
constexpr size_t OFF_BAR  = OFF_HRTL + 131072;            // 4096 ints of flag state
constexpr size_t OFF_END  = OFF_BAR + 4096;

__device__ __forceinline__ ushort f2bf(float f) {
    unsigned u = __float_as_uint(f);
    u = u + 0x7FFF + ((u >> 16) & 1);
    return (ushort)(u >> 16);
}
__device__ __forceinline__ float bf2f(ushort h) {
    return __uint_as_float(((unsigned)h) << 16);
}
// fragment-linear LDS layout for a 16x64 bf16 A-operand panel:
// value (m,k) lives at (k>>5)*512 + ((k>>3)&3)*128 + m*8 + (k&7)
__device__ __forceinline__ int fragaddr(int m, int k) {
    return ((k >> 5) << 9) + (((k >> 3) & 3) << 7) + (m << 3) + (k & 7);
}

#define MFMA16(a, b, c) __builtin_amdgcn_mfma_f32_16x16x32_bf16((a), (b), (c), 0, 0, 0)

// ---------------- setup kernels ----------------
__global__ void k_deg(const float* __restrict__ w, const int* __restrict__ src,
                      float* __restrict__ deg) {
    int e = blockIdx.x * 256 + threadIdx.x;
    if (e < En) atomicAdd(&deg[src[e]], w[e]);
}

__global__ void k_dinv(const float* __restrict__ deg, float* __restrict__ dinv) {
    int n = blockIdx.x * 256 + threadIdx.x;
    if (n < Nn) {
        float d = deg[n];
        dinv[n] = d > 0.f ? rsqrtf(fmaxf(d, 1e-12f)) : 0.f;
    }
}

__global__ void k_nwdense(const float* __restrict__ w, const int* __restrict__ src,
                          const int* __restrict__ dst, const float* __restrict__ dinv,
                          float* __restrict__ L1d) {
    int e = blockIdx.x * 256 + threadIdx.x;
    if (e < En) {
        int s = src[e], d = dst[e];
        float nw = -w[e] * dinv[s] * dinv[d];
        atomicAdd(&L1d[d * Nn + s], nw);
    }
}

// L2 = 2*(L1@L1) - I.  64 blocks x 1024 threads (4 waves/SIMD), 2x2 per thread.
__global__ __launch_bounds__(1024) void k_l2(const float* __restrict__ A,
                                             float* __restrict__ C) {
    __shared__ float As[64][33];
    __shared__ float Bs[32][65];
    int t = threadIdx.x;
    int i0 = (blockIdx.x >> 3) * 64;
    int j0 = (blockIdx.x & 7) * 64;
    int tx = t & 31, ty = t >> 5;          // 32x32 threads, each 2x2
    float acc[2][2] = {};
    int ar = t >> 4, ac = (t & 15) * 2;    // A stage: 64 rows x 32 k
    int br = t >> 5, bc = (t & 31) * 2;    // B stage: 32 k x 64 j
    for (int kc = 0; kc < 512; kc += 32) {
        float2 a2 = *(const float2*)&A[(size_t)(i0 + ar) * 512 + kc + ac];
        float2 b2 = *(const float2*)&A[(size_t)(kc + br) * 512 + j0 + bc];
        As[ar][ac] = a2.x; As[ar][ac + 1] = a2.y;
        Bs[br][bc] = b2.x; Bs[br][bc + 1] = b2.y;
        __syncthreads();
#pragma unroll 8
        for (int kk = 0; kk < 32; kk++) {
            float a0 = As[ty * 2][kk], a1 = As[ty * 2 + 1][kk];
            float b0 = Bs[kk][tx * 2], b1 = Bs[kk][tx * 2 + 1];
            acc[0][0] += a0 * b0; acc[0][1] += a0 * b1;
            acc[1][0] += a1 * b0; acc[1][1] += a1 * b1;
        }
        __syncthreads();
    }
#pragma unroll
    for (int r = 0; r < 2; r++)
#pragma unroll
        for (int c = 0; c < 2; c++) {
            int i = i0 + ty * 2 + r, j = j0 + tx * 2 + c;
            C[(size_t)i * 512 + j] = 2.f * acc[r][c] - (i == j ? 1.f : 0.f);
        }
}

// L1/L2 -> bf16 split A-fragments; idx = ((mat*32+rb)*16 + kc)*512 + lane*8 + j
__global__ void k_lfrag(const float* __restrict__ L1, const float* __restrict__ L2,
                        ushort* __restrict__ AfH, ushort* __restrict__ AfL) {
    int idx = blockIdx.x * 256 + threadIdx.x;   // 0..524287
    int j = idx & 7;
    int lane = (idx >> 3) & 63;
    int kc = (idx >> 9) & 15;
    int rb = (idx >> 13) & 31;
    int mat = idx >> 18;
    int row = rb * 16 + (lane & 15);
    int k = kc * 32 + (lane >> 4) * 8 + j;
    float v = (mat ? L2 : L1)[(size_t)row * 512 + k];
    ushort hi = f2bf(v);
    AfH[idx] = hi;
    AfL[idx] = f2bf(v - bf2f(hi));
}

// Wzr/Wht -> bf16 split B-fragments: idx = ((l*CT + ct)*12 + kc)*512 + lane*8 + j
__global__ void k_wfrag(const float* __restrict__ WzrC, const float* __restrict__ WhC,
                        ushort* __restrict__ WzFH, ushort* __restrict__ WzFL,
                        ushort* __restrict__ WhFH, ushort* __restrict__ WhFL) {
    int idx = blockIdx.x * 256 + threadIdx.x;
    if (idx < 98304) {
        int l = idx / 49152, off = idx % 49152;
        int tile = off >> 9, r = off & 511;
        int lane = r >> 3, j = r & 7;
        int ct = tile / 12, kc = tile % 12;
        int k = kc * 32 + (lane >> 4) * 8 + j;
        int n = ct * 16 + (lane & 15);
        float v = WzrC[(size_t)l * 49152 + k * 128 + n];
        ushort hi = f2bf(v);
        WzFH[idx] = hi;
        WzFL[idx] = f2bf(v - bf2f(hi));
    } else if (idx < 147456) {
        int t2 = idx - 98304;
        int l = t2 / 24576, off = t2 % 24576;
        int tile = off >> 9, r = off & 511;
        int lane = r >> 3, j = r & 7;
        int ct = tile / 12, kc = tile % 12;
        int k = kc * 32 + (lane >> 4) * 8 + j;
        int n = ct * 16 + (lane & 15);
        float v = WhC[(size_t)l * 24576 + k * 64 + n];
        ushort hi = f2bf(v);
        WhFH[t2] = hi;
        WhFL[t2] = f2bf(v - bf2f(hi));
    }
}

// ---------------- MFMA T1x/T2x: o1 = L1@x, o2 = L2@x per slice ----------------
__global__ __launch_bounds__(256) void k_lxm(
        const ushort* __restrict__ AfH, const ushort* __restrict__ AfL,
        const float* __restrict__ in, float* __restrict__ o1, float* __restrict__ o2) {
    __shared__ ushort Bh[2][2176];   // [buf][n*34 + k] (pad 34 halves)
    __shared__ ushort Bl[2][2176];
    int slice = blockIdx.x >> 3;
    int rg = blockIdx.x & 7;
    const float* xs = in + (size_t)slice * NC;
    int tid = threadIdx.x;
    int lane = tid & 63, wav = tid >> 6;
    int quad = lane >> 4, l15 = lane & 15;
    int sn = tid & 63, skq = tid >> 6;
    int rt = rg * 4 + wav;
    size_t abA = ((size_t)rt * 16) * 512 + lane * 8;        // L1 rows
    size_t abB = ((size_t)(32 + rt) * 16) * 512 + lane * 8; // L2 rows
    f32x4 accA[4], accB[4];
#pragma unroll
    for (int n = 0; n < 4; n++) {
        accA[n] = (f32x4){0.f, 0.f, 0.f, 0.f};
        accB[n] = (f32x4){0.f, 0.f, 0.f, 0.f};
    }
    {
        short8 hi8, lo8;
#pragma unroll
        for (int i = 0; i < 8; i++) {
            float v = xs[(size_t)(skq * 8 + i) * 64 + sn];
            ushort hv = f2bf(v);
            hi8[i] = (short)hv;
            lo8[i] = (short)f2bf(v - bf2f(hv));
        }
        *(short8*)&Bh[0][sn * 34 + skq * 8] = hi8;
        *(short8*)&Bl[0][sn * 34 + skq * 8] = lo8;
    }
    __syncthreads();
#pragma unroll
    for (int kc = 0; kc < 16; kc++) {
        const int cur = kc & 1;
        float sv[8];
        if (kc < 15) {
#pragma unroll
            for (int i = 0; i < 8; i++)
                sv[i] = xs[(size_t)((kc + 1) * 32 + skq * 8 + i) * 64 + sn];
        }
        size_t o = (size_t)kc * 512;
        short8 lah = *(const short8*)&AfH[abA + o];
        short8 lal = *(const short8*)&AfL[abA + o];
        short8 lbh = *(const short8*)&AfH[abB + o];
        short8 lbl = *(const short8*)&AfL[abB + o];
#pragma unroll
        for (int nt = 0; nt < 4; nt++) {
            short8 xh = *(const short8*)&Bh[cur][(nt * 16 + l15) * 34 + quad * 8];
            short8 xl = *(const short8*)&Bl[cur][(nt * 16 + l15) * 34 + quad * 8];
            accA[nt] = MFMA16(lah, xh, accA[nt]);
            accA[nt] = MFMA16(lah, xl, accA[nt]);
            accA[nt] = MFMA16(lal, xh, accA[nt]);
            accB[nt] = MFMA16(lbh, xh, accB[nt]);
            accB[nt] = MFMA16(lbh, xl, accB[nt]);
            accB[nt] = MFMA16(lbl, xh, accB[nt]);
        }
        if (kc < 15) {
            short8 hi8, lo8;
#pragma unroll
            for (int i = 0; i < 8; i++) {
                ushort hv = f2bf(sv[i]);
                hi8[i] = (short)hv;
                lo8[i] = (short)f2bf(sv[i] - bf2f(hv));
            }
            *(short8*)&Bh[cur ^ 1][sn * 34 + skq * 8] = hi8;
            *(short8*)&Bl[cur ^ 1][sn * 34 + skq * 8] = lo8;
        }
        __syncthreads();
    }
    float* os1 = o1 + (size_t)slice * NC;
    float* os2 = o2 + (size_t)slice * NC;
#pragma unroll
    for (int nt = 0; nt < 4; nt++)
#pragma unroll
        for (int reg = 0; reg < 4; reg++) {
            size_t row = (size_t)(rt * 16 + quad * 4 + reg);
            os1[row * 64 + nt * 16 + l15] = accA[nt][reg];
            os2[row * 64 + nt * 16 + l15] = accB[nt][reg];
        }
}

// repack weights.  A-column order: [h | x | T1x | T2x | U1 | U2] so that
// k-tiles 0..7 depend only on block-local data and 8..11 on the exchanged U1/U2.
__global__ void k_repack(const float* __restrict__ Wx, const float* __restrict__ bx,
                         const float* __restrict__ Wh, const float* __restrict__ bh,
                         const float* __restrict__ W1,
                         float* __restrict__ WzrC, float* __restrict__ WhC,
                         float* __restrict__ bzr, float* __restrict__ bht,
                         float* __restrict__ W1cat) {
    int idx = blockIdx.x * 256 + threadIdx.x;
    if (idx < 98304) {
        int l = idx / 49152, r = idx % 49152;
        int k = r / 128, j = r % 128;
        int g = j >> 6, hh = j & 63;
        int kc, c; const float* s;
        if (k < 64)       { kc = 0; c = k; s = Wh; }
        else if (k < 256) { kc = (k - 64) >> 6; c = (k - 64) & 63; s = Wx; }
        else              { kc = 1 + ((k - 256) >> 6); c = (k - 256) & 63; s = Wh; }
        WzrC[idx] = s[((((size_t)(l*3 + g))*3 + kc)*64 + c)*64 + hh];
    } else if (idx < 147456) {
        int tI = idx - 98304;
        int l = tI / 24576, r = tI % 24576;
        int k = r / 64, hh = r % 64;
        int kc, c; const float* s;
        if (k < 64)       { kc = 0; c = k; s = Wh; }
        else if (k < 256) { kc = (k - 64) >> 6; c = (k - 64) & 63; s = Wx; }
        else              { kc = 1 + ((k - 256) >> 6); c = (k - 256) & 63; s = Wh; }
        WhC[tI] = s[((((size_t)(l*3 + 2))*3 + kc)*64 + c)*64 + hh];
    } else if (idx < 147712) {
        int tI = idx - 147456;
        int l = tI >> 7, j = tI & 127;
        int g = j >> 6, hh = j & 63;
        bzr[tI] = bh[(l*3 + g)*64 + hh] + bx[(l*3 + g)*64 + hh];
    } else if (idx < 147840) {
        int tI = idx - 147712;
        int l = tI >> 6, hh = tI & 63;
        bht[tI] = bh[(l*3 + 2)*64 + hh] + bx[(l*3 + 2)*64 + hh];
    } else if (idx < 156032) {
        int tI = idx - 147840;
        int c = tI >> 7, j = tI & 127;
        W1cat[tI] = (j < 64) ? W1[c*64 + j] : W1[(64 + c)*64 + (j - 64)];
    }
}

// ================= persistent recurrence kernel =================
// Round-6 proven structure (best measured: k_recur 484 us, total 682 us):
// 256 blocks x 256 threads, L-panels in LDS, arrive/wait split, phase-B
// pre/post split, payload via wide coherent vector ops (sc0 sc1) + epoch
// flags via relaxed agent atomics, NO fences.  (XCD-local variant from
// rounds 8-9 removed: hang-capable if HW_REG_XCC_ID misreads uniformly.)

__device__ __forceinline__ void wait_flags(int* gflags, int epoch) {
    if (threadIdx.x < 64) {
        bool done = threadIdx.x >= 32;
        while (!__all(done)) {
            if (!done)
                done = __hip_atomic_load(&gflags[threadIdx.x * 16],
                                         __ATOMIC_RELAXED,
                                         __HIP_MEMORY_SCOPE_AGENT) >= epoch;
            if (!__all(done)) __builtin_amdgcn_s_sleep(1);
        }
    }
    __syncthreads();
}

__device__ __forceinline__ void arrive(int* gflags, int rowblk, int epoch) {
    // inline-asm payload stores are NOT tracked by the compiler's waitcnt
    // model: drain them explicitly before the barrier, then publish the flag.
    asm volatile("s_waitcnt vmcnt(0)" ::: "memory");
    __syncthreads();
    if (threadIdx.x == 0)
        __hip_atomic_store(&gflags[rowblk * 16], epoch,
                           __ATOMIC_RELAXED, __HIP_MEMORY_SCOPE_AGENT);
}

// write S (fp32 [16][64]) as bf16 transposed [64 cols][16 rows of this block].
// 128 threads x one 16B coherent vector store (sc0 sc1 = write to MALL).
__device__ __forceinline__ void store_T_pay(ushort* dstB, const float* S,
                                            int n0, int tid) {
    if (tid < 128) {
        int c = tid >> 1, half = tid & 1;   // col 0..63, node-octet 0..1
        short8 v;
#pragma unroll
        for (int j = 0; j < 8; j++)
            v[j] = (short)f2bf(S[(half * 8 + j) * 64 + c]);
        asm volatile("global_store_dwordx4 %0, %1, off sc0 sc1"
                     :: "v"(dstB + (size_t)c * 512 + n0 + half * 8), "v"(v)
                     : "memory");
    }
}

// stage segs 1,2,3 (x, T1x, T2x) — identical for l=0/1, so once per t
__device__ __forceinline__ void stage_xsegs(
        ushort* AH, ushort* AL, const float* __restrict__ x,
        const float* __restrict__ t1x, const float* __restrict__ t2x,
        size_t xoff, int tid) {
    int p = tid * 4;
    int m = p >> 6, kb = p & 63;
    int fa = fragaddr(m, kb);
    const float* srcs[3] = { x + xoff, t1x + xoff, t2x + xoff };
    const int sidx[3] = { 1, 2, 3 };
#pragma unroll
    for (int q = 0; q < 3; q++) {
        float4 v = *(const float4*)&srcs[q][(size_t)m * 64 + kb];
        float vv[4] = { v.x, v.y, v.z, v.w };
        int base = sidx[q] * 1024 + fa;
#pragma unroll
        for (int j = 0; j < 4; j++) {
            ushort hi = f2bf(vv[j]);
            AH[base + j] = hi;
            AL[base + j] = f2bf(vv[j] - bf2f(hi));
        }
    }
}

// stage seg 0 from an LDS-resident fp32 16x64 buffer (h or hr)
__device__ __forceinline__ void stage_h_lds(ushort* AH, ushort* AL,
                                            const float* hs, int tid) {
    int p = tid * 4;
    int m = p >> 6, kb = p & 63;
    int fa = fragaddr(m, kb);
#pragma unroll
    for (int j = 0; j < 4; j++) {
        float v = hs[m * 64 + kb + j];
        ushort hi = f2bf(v);
        AH[fa + j] = hi;
        AL[fa + j] = f2bf(v - bf2f(hi));
    }
}

// phase A: U1 = L1[rows,:]@src, U2 = L2[rows,:]@src via split-bf16 MFMA.
// A-side from LDS-cached panels; B-side (transposed h/hr, bf16 hi only):
// 16 wide coherent loads issued back-to-back, one vmcnt(0) drain, then MFMA.
// Writes U1 -> seg 4, U2 -> seg 5.
__device__ __forceinline__ void phase_A16_p(
        ushort* AH, ushort* AL, const ushort* LAH, const ushort* LAL,
        const ushort* __restrict__ sTh, int tid) {
    int lane = tid & 63, wav = tid >> 6;
    int quad = lane >> 4, l15 = lane & 15;
    int ab1 = lane * 8;
    int ab2 = 8192 + lane * 8;
    size_t bb = (size_t)(wav * 16 + l15) * 512 + quad * 8;
    f32x4 p1a = {0.f,0.f,0.f,0.f}, p1c = p1a, p2a = p1a, p2c = p1a;
    short8 bh[16];
#pragma unroll
    for (int s = 0; s < 16; s++) {
        asm volatile("global_load_dwordx4 %0, %1, off sc0 sc1"
                     : "=v"(bh[s]) : "v"(sTh + bb + (size_t)s * 32) : "memory");
    }
    asm volatile("s_waitcnt vmcnt(0)" ::: "memory");
    __builtin_amdgcn_sched_barrier(0);
    short8 a1h[2], a1l[2], a2h[2], a2l[2];
#pragma unroll
    for (int s = 0; s < 2; s++) {
        int o = s * 512;
        a1h[s] = *(const short8*)&LAH[ab1 + o];
        a1l[s] = *(const short8*)&LAL[ab1 + o];
        a2h[s] = *(const short8*)&LAH[ab2 + o];
        a2l[s] = *(const short8*)&LAL[ab2 + o];
    }
#pragma unroll
    for (int kc = 0; kc < 16; kc++) {
        int sa = kc & 1;
        p1a = MFMA16(a1h[sa], bh[kc], p1a);
        p1c = MFMA16(a1l[sa], bh[kc], p1c);
        p2a = MFMA16(a2h[sa], bh[kc], p2a);
        p2c = MFMA16(a2l[sa], bh[kc], p2c);
        if (kc + 2 < 16) {
            int o = (kc + 2) * 512;
            a1h[sa] = *(const short8*)&LAH[ab1 + o];
            a1l[sa] = *(const short8*)&LAL[ab1 + o];
            a2h[sa] = *(const short8*)&LAH[ab2 + o];
            a2l[sa] = *(const short8*)&LAL[ab2 + o];
        }
    }
    int colA = wav * 16 + l15;
#pragma unroll
    for (int reg = 0; reg < 4; reg++) {
        int row = quad * 4 + reg;
        float u1 = p1a[reg] + p1c[reg];
        float u2 = p2a[reg] + p2c[reg];
        ushort h1 = f2bf(u1), h2 = f2bf(u2);
        int fa1 = 4096 + fragaddr(row, colA);
        int fa2 = 5120 + fragaddr(row, colA);
        AH[fa1] = h1; AL[fa1] = f2bf(u1 - bf2f(h1));
        AH[fa2] = h2; AL[fa2] = f2bf(u2 - bf2f(h2));
    }
}

// phase B1 pre: kt 0..7 (segs h,x,T1x,T2x) — runs BEFORE the payload wait.
__device__ __forceinline__ void phase_B1_pre(
        const ushort* AH, const ushort* AL,
        const ushort* __restrict__ WFH, const ushort* __restrict__ WFL,
        f32x4* q, int tid) {
    int lane = tid & 63, wav = tid >> 6;
    int quad = lane >> 4, l15 = lane & 15;
    int abase = quad * 128 + l15 * 8;
    size_t w0 = ((size_t)wav * 12) * 512 + lane * 8;
    size_t w1 = ((size_t)(4 + wav) * 12) * 512 + lane * 8;
    short8 ah[2], al[2], w0h[4], w0l[4], w1h[4], w1l[4];
#pragma unroll
    for (int s = 0; s < 2; s++) {
        ah[s] = *(const short8*)&AH[abase + s * 512];
        al[s] = *(const short8*)&AL[abase + s * 512];
    }
#pragma unroll
    for (int s = 0; s < 4; s++) {
        size_t o = (size_t)s * 512;
        w0h[s] = *(const short8*)&WFH[w0 + o];
        w0l[s] = *(const short8*)&WFL[w0 + o];
        w1h[s] = *(const short8*)&WFH[w1 + o];
        w1l[s] = *(const short8*)&WFL[w1 + o];
    }
#pragma unroll
    for (int kt = 0; kt < 8; kt++) {
        int sa = kt & 1, sw = kt & 3;
        q[0] = MFMA16(ah[sa], w0h[sw], q[0]);
        q[1] = MFMA16(ah[sa], w0l[sw], q[1]);
        q[2] = MFMA16(al[sa], w0h[sw], q[2]);
        q[3] = MFMA16(ah[sa], w1h[sw], q[3]);
        q[4] = MFMA16(ah[sa], w1l[sw], q[4]);
        q[5] = MFMA16(al[sa], w1h[sw], q[5]);
        if (kt + 2 < 8) {
            ah[sa] = *(const short8*)&AH[abase + (kt + 2) * 512];
            al[sa] = *(const short8*)&AL[abase + (kt + 2) * 512];
        }
        if (kt + 4 < 8) {
            size_t o = (size_t)(kt + 4) * 512;
            w0h[sw] = *(const short8*)&WFH[w0 + o];
            w0l[sw] = *(const short8*)&WFL[w0 + o];
            w1h[sw] = *(const short8*)&WFH[w1 + o];
            w1l[sw] = *(const short8*)&WFL[w1 + o];
        }
    }
}

// phase B1 post: kt 8..11 (U1,U2) — after phase A; writes PRED.
__device__ __forceinline__ void phase_B1_post(
        const ushort* AH, const ushort* AL,
        const ushort* __restrict__ WFH, const ushort* __restrict__ WFL,
        f32x4* q, float* PRED, int tid) {
    int lane = tid & 63, wav = tid >> 6;
    int quad = lane >> 4, l15 = lane & 15;
    int abase = quad * 128 + l15 * 8;
    size_t w0 = ((size_t)wav * 12) * 512 + lane * 8;
    size_t w1 = ((size_t)(4 + wav) * 12) * 512 + lane * 8;
    short8 ah[4], al[4], w0h[4], w0l[4], w1h[4], w1l[4];
#pragma unroll
    for (int s = 0; s < 4; s++) {
        int o = (8 + s) * 512;
        ah[s] = *(const short8*)&AH[abase + o];
        al[s] = *(const short8*)&AL[abase + o];
        size_t wo = (size_t)(8 + s) * 512;
        w0h[s] = *(const short8*)&WFH[w0 + wo];
        w0l[s] = *(const short8*)&WFL[w0 + wo];
        w1h[s] = *(const short8*)&WFH[w1 + wo];
        w1l[s] = *(const short8*)&WFL[w1 + wo];
    }
#pragma unroll
    for (int kt = 0; kt < 4; kt++) {
        q[0] = MFMA16(ah[kt], w0h[kt], q[0]);
        q[1] = MFMA16(ah[kt], w0l[kt], q[1]);
        q[2] = MFMA16(al[kt], w0h[kt], q[2]);
        q[3] = MFMA16(ah[kt], w1h[kt], q[3]);
        q[4] = MFMA16(ah[kt], w1l[kt], q[4]);
        q[5] = MFMA16(al[kt], w1h[kt], q[5]);
    }
#pragma unroll
    for (int reg = 0; reg < 4; reg++) {
        int row = quad * 4 + reg;
        PRED[row * 128 + wav * 16 + l15] = q[0][reg] + q[1][reg] + q[2][reg];
        PRED[row * 128 + 64 + wav * 16 + l15] = q[3][reg] + q[4][reg] + q[5][reg];
    }
}

// phase B2 pre/post: ht[16][64] = A[16][384] @ Wht
__device__ __forceinline__ void phase_B2_pre(
        const ushort* AH, const ushort* AL,
        const ushort* __restrict__ WFH, const ushort* __restrict__ WFL,
        f32x4* q, int tid) {
    int lane = tid & 63, wav = tid >> 6;
    int quad = lane >> 4, l15 = lane & 15;
    int abase = quad * 128 + l15 * 8;
    size_t w0 = ((size_t)wav * 12) * 512 + lane * 8;
    short8 ah[2], al[2], wh[4], wl[4];
#pragma unroll
    for (int s = 0; s < 2; s++) {
        ah[s] = *(const short8*)&AH[abase + s * 512];
        al[s] = *(const short8*)&AL[abase + s * 512];
    }
#pragma unroll
    for (int s = 0; s < 4; s++) {
        wh[s] = *(const short8*)&WFH[w0 + (size_t)s * 512];
        wl[s] = *(const short8*)&WFL[w0 + (size_t)s * 512];
    }
#pragma unroll
    for (int kt = 0; kt < 8; kt++) {
        int sa = kt & 1, sw = kt & 3;
        q[0] = MFMA16(ah[sa], wh[sw], q[0]);
        q[1] = MFMA16(ah[sa], wl[sw], q[1]);
        q[2] = MFMA16(al[sa], wh[sw], q[2]);
        if (kt + 2 < 8) {
            ah[sa] = *(const short8*)&AH[abase + (kt + 2) * 512];
            al[sa] = *(const short8*)&AL[abase + (kt + 2) * 512];
        }
        if (kt + 4 < 8) {
            size_t o = (size_t)(kt + 4) * 512;
            wh[sw] = *(const short8*)&WFH[w0 + o];
            wl[sw] = *(const short8*)&WFL[w0 + o];
        }
    }
}

__device__ __forceinline__ void phase_B2_post(
        const ushort* AH, const ushort* AL,
        const ushort* __restrict__ WFH, const ushort* __restrict__ WFL,
        f32x4* q, float* PRED, int tid) {
    int lane = tid & 63, wav = tid >> 6;
    int quad = lane >> 4, l15 = lane & 15;
    int abase = quad * 128 + l15 * 8;
    size_t w0 = ((size_t)wav * 12) * 512 + lane * 8;
    short8 ah[4], al[4], wh[4], wl[4];
#pragma unroll
    for (int s = 0; s < 4; s++) {
        int o = (8 + s) * 512;
        ah[s] = *(const short8*)&AH[abase + o];
        al[s] = *(const short8*)&AL[abase + o];
        size_t wo = (size_t)(8 + s) * 512;
        wh[s] = *(const short8*)&WFH[w0 + wo];
        wl[s] = *(const short8*)&WFL[w0 + wo];
    }
#pragma unroll
    for (int kt = 0; kt < 4; kt++) {
        q[0] = MFMA16(ah[kt], wh[kt], q[0]);
        q[1] = MFMA16(ah[kt], wl[kt], q[1]);
        q[2] = MFMA16(al[kt], wh[kt], q[2]);
    }
#pragma unroll
    for (int reg = 0; reg < 4; reg++)
        PRED[(quad * 4 + reg) * 64 + wav * 16 + l15] = q[0][reg] + q[1][reg] + q[2][reg];
}

__global__ __launch_bounds__(256) void k_recur(
        const float* __restrict__ x, const float* __restrict__ t1x,
        const float* __restrict__ t2x,
        const ushort* __restrict__ AfH, const ushort* __restrict__ AfL,
        const ushort* __restrict__ WzFH, const ushort* __restrict__ WzFL,
        const ushort* __restrict__ WhFH, const ushort* __restrict__ WhFL,
        const float* __restrict__ bzr, const float* __restrict__ bht,
        float* __restrict__ h, ushort* __restrict__ hTh,
        ushort* __restrict__ hrTh, int* __restrict__ bar) {
    __shared__ __attribute__((aligned(16))) ushort AH[6144];    // 12 KB
    __shared__ __attribute__((aligned(16))) ushort AL[6144];    // 12 KB
    __shared__ __attribute__((aligned(16))) float  PRED[2048];  //  8 KB
    __shared__ __attribute__((aligned(16))) float  HS[1024];    //  4 KB (persistent h)
    __shared__ __attribute__((aligned(16))) float  ZS[1024];    //  4 KB (z gate)
    __shared__ __attribute__((aligned(16))) float  HRS[1024];   //  4 KB (h*r)
    __shared__ __attribute__((aligned(16))) ushort LAH[16384];  // 32 KB L1|L2 panels hi
    __shared__ __attribute__((aligned(16))) ushort LAL[16384];  // 32 KB lo
    int tid = threadIdx.x;
    int b = blockIdx.x & 7;          // XCD-affine grouping (perf heuristic only)
    int rowblk = blockIdx.x >> 3;
    int n0 = rowblk * 16;
    int* gflags = bar + b * 512;     // 32 slots x 16 ints (64 B apart)

    // one-time: this block's L panels -> LDS (fixed for all 64 steps); h = 0
    for (int i = tid; i < 1024; i += 256) {
        *(short8*)&LAH[i * 8] = *(const short8*)&AfH[(size_t)rowblk * 8192 + i * 8];
        *(short8*)&LAL[i * 8] = *(const short8*)&AfL[(size_t)rowblk * 8192 + i * 8];
        *(short8*)&LAH[8192 + i * 8] = *(const short8*)&AfH[(size_t)(32 + rowblk) * 8192 + i * 8];
        *(short8*)&LAL[8192 + i * 8] = *(const short8*)&AfL[(size_t)(32 + rowblk) * 8192 + i * 8];
    }
    for (int i = tid; i < 1024; i += 256) HS[i] = 0.f;
    __syncthreads();

    ushort* hThB = hTh + (size_t)b * 32768;
    ushort* hrThB = hrTh + (size_t)b * 32768;
    int ep = 0;
#pragma unroll 1
    for (int t = 0; t < Tn; t++) {
        size_t xoff = ((size_t)(b * Tn + t) * Nn + n0) * 64;
        stage_xsegs(AH, AL, x, t1x, t2x, xoff, tid);   // segs 1..3, shared by l=0/1
#pragma unroll 1
        for (int l = 0; l < Ln; l++) {
            const ushort* WzH = WzFH + (size_t)l * 49152;
            const ushort* WzL = WzFL + (size_t)l * 49152;
            const ushort* WtH = WhFH + (size_t)l * 24576;
            const ushort* WtL = WhFL + (size_t)l * 24576;
            const float* bz = bzr + l * 128;
            const float* bt = bht + l * 64;
            // ---- half-cell 1: z,r gates; hr = h*r ----
            stage_h_lds(AH, AL, HS, tid);
            __syncthreads();
            f32x4 q[6];
#pragma unroll
            for (int i = 0; i < 6; i++) q[i] = (f32x4){0.f,0.f,0.f,0.f};
            phase_B1_pre(AH, AL, WzH, WzL, q, tid);       // local kt 0..7
            wait_flags(gflags, ep);                        // previous arrivals
            phase_A16_p(AH, AL, LAH, LAL, hThB, tid);      // payload -> U1,U2
            __syncthreads();
            phase_B1_post(AH, AL, WzH, WzL, q, PRED, tid); // kt 8..11 + write
            __syncthreads();
            for (int i = tid; i < 2048; i += 256) {
                int r = i >> 7, c = i & 127;
                float v = PRED[i] + bz[c];
                float s = 1.f / (1.f + __expf(-v));
                if (c < 64) {
                    ZS[r * 64 + c] = s;
                } else {
                    int c2 = c - 64;
                    HRS[r * 64 + c2] = HS[r * 64 + c2] * s;
                }
            }
            __syncthreads();
            store_T_pay(hrThB, HRS, n0, tid);
            arrive(gflags, rowblk, ep + 1);
            ep++;
            // ---- half-cell 2: ht; h = z*h + (1-z)*ht ----
            stage_h_lds(AH, AL, HRS, tid);
            __syncthreads();
            f32x4 r3[3];
#pragma unroll
            for (int i = 0; i < 3; i++) r3[i] = (f32x4){0.f,0.f,0.f,0.f};
            phase_B2_pre(AH, AL, WtH, WtL, r3, tid);
            wait_flags(gflags, ep);
            phase_A16_p(AH, AL, LAH, LAL, hrThB, tid);
            __syncthreads();
            phase_B2_post(AH, AL, WtH, WtL, r3, PRED, tid);
            __syncthreads();
            for (int i = tid; i < 1024; i += 256) {
                int c = i & 63;
                float v = PRED[i] + bt[c];
                // fast tanh (NaN-safe)
                float av = fabsf(v);
                float e2 = __expf(-2.f * av);
                float m = (1.f - e2) / (1.f + e2);
                float htv = v < 0.f ? -m : m;
                float zz = ZS[i], hold = HS[i];
                float hn = zz * hold + (1.f - zz) * htv;
                HS[i] = hn;
                if (t == Tn - 1 && l == Ln - 1)
                    h[((size_t)(b * Nn + n0 + (i >> 6))) * 64 + c] = hn;
            }
            __syncthreads();
            store_T_pay(hThB, HS, n0, tid);
            arrive(gflags, rowblk, ep + 1);
            ep++;
        }
    }
}

// ---------------- projections ----------------
__global__ __launch_bounds__(256) void k_proj(
        const float* __restrict__ h, const float* __restrict__ W1cat,
        const float* __restrict__ b1,
        float* __restrict__ sproj, float* __restrict__ tproj) {
    __shared__ float As[16][33];
    __shared__ float Ws[16 * 128];
    int tid = threadIdx.x;
    int row0 = blockIdx.x * 32;
    const float* hp = h + (size_t)row0 * 64;
    float acc[2][8] = {};
    int tx = tid & 15, ty = tid >> 4;
    int lr = tid >> 3;
    int lk = (tid & 7) * 2;
    int wk = tid >> 4;
    int wc = (tid & 15) * 8;
    for (int kt = 0; kt < 4; kt++) {
        int c0 = kt * 16;
        float2 a2 = *(const float2*)&hp[lr * 64 + c0 + lk];
        const float4* wsrc = (const float4*)&W1cat[(size_t)(kt * 16 + wk) * 128 + wc];
        float4 w0 = wsrc[0], w1 = wsrc[1];
        As[lk][lr] = a2.x;
        As[lk + 1][lr] = a2.y;
        *(float4*)&Ws[wk * 128 + wc] = w0;
        *(float4*)&Ws[wk * 128 + wc + 4] = w1;
        __syncthreads();
#pragma unroll
        for (int kk = 0; kk < 16; kk++) {
            float a0 = As[kk][ty * 2 + 0];
            float a1 = As[kk][ty * 2 + 1];
            float4 p0 = *(const float4*)&Ws[kk * 128 + tx * 8];
            float4 p1 = *(const float4*)&Ws[kk * 128 + tx * 8 + 4];
            float w[8] = { p0.x, p0.y, p0.z, p0.w, p1.x, p1.y, p1.z, p1.w };
#pragma unroll
            for (int cc = 0; cc < 8; cc++) {
                acc[0][cc] += a0 * w[cc];
                acc[1][cc] += a1 * w[cc];
            }
        }
        __syncthreads();
    }
#pragma unroll
    for (int rr = 0; rr < 2; rr++) {
        int row = row0 + ty * 2 + rr;
#pragma unroll
        for (int cc = 0; cc < 8; cc++) {
            int col = tx * 8 + cc;
            float v = acc[rr][cc];
            if (col < 64) sproj[(size_t)row * 64 + col] = v + b1[col];
            else tproj[(size_t)row * 64 + (col - 64)] = v;
        }
    }
}

// ---------------- logits ----------------
__global__ __launch_bounds__(256) void k_logits(
        const float* __restrict__ sproj, const float* __restrict__ tproj,
        const float* __restrict__ W2, const float* __restrict__ b2,
        float* __restrict__ out) {
    __shared__ float sp[32 * 64];
    __shared__ float tp[64 * 65];
    __shared__ float w2s[64];
    int tid = threadIdx.x;
    int bb = blockIdx.x >> 7;
    int st = (blockIdx.x >> 3) & 15;
    int tt = blockIdx.x & 7;
    const float* spg = sproj + ((size_t)bb * Nn + st * 32) * 64;
    const float* tpg = tproj + ((size_t)bb * Nn + tt * 64) * 64;
    for (int i = tid; i < 2048; i += 256) sp[i] = spg[i];
    for (int i = tid; i < 4096; i += 256) {
        int tl = i >> 6, hh = i & 63;
        tp[tl * 65 + hh] = tpg[i];
    }
    if (tid < 64) w2s[tid] = W2[tid];
    __syncthreads();
    float bias = *b2;
    int tl = tid & 63, sg = tid >> 6;
    for (int si = 0; si < 8; si++) {
        int s = sg * 8 + si;
        float acc = bias;
#pragma unroll 8
        for (int hh = 0; hh < 64; hh++) {
            float v = sp[s * 64 + hh] + tp[tl * 65 + hh];
            acc += fmaxf(v, 0.f) * w2s[hh];
        }
        out[(size_t)bb * Nn * Nn + (size_t)(st * 32 + s) * Nn + tt * 64 + tl] = acc;
    }
}

// ---------------- host ----------------
extern "C" void kernel_launch(void* const* d_in, const int* in_sizes, int n_in,
                              void* d_out, int out_size, void* d_ws, size_t ws_size,
                              hipStream_t stream) {
    const float* x  = (const float*)d_in[0];
    const float* ew = (const float*)d_in[1];
    const float* Wx = (const float*)d_in[2];
    const float* bx = (const float*)d_in[3];
    const float* Wh = (const float*)d_in[4];
    const float* bh = (const float*)d_in[5];
    const float* W1 = (const float*)d_in[6];
    const float* b1 = (const float*)d_in[7];
    const float* W2 = (const float*)d_in[8];
    const float* b2 = (const float*)d_in[9];
    const int* ei   = (const int*)d_in[10];
    const int* esrc = ei;
    const int* edst = ei + En;

    float* ws = (float*)d_ws;
    float* deg   = ws + OFF_DEG;
    float* dinv  = ws + OFF_DINV;
    float* L1d   = ws + OFF_L1D;
    float* L2d   = ws + OFF_L2D;
    float* WzrC  = ws + OFF_WZR;
    float* WhC   = ws + OFF_WHT;
    float* bzr   = ws + OFF_BZR;
    float* bht   = ws + OFF_BHT;
    float* W1cat = ws + OFF_W1C;
    float* T1x   = ws + OFF_T1X;
    float* T2x   = ws + OFF_T2X;
    float* h     = ws + OFF_H;
    float* sproj = ws + OFF_SP;
    float* tproj = ws + OFF_TP;
    ushort* AfH  = (ushort*)(ws + OFF_LFH);
    ushort* AfL  = (ushort*)(ws + OFF_LFL);
    ushort* hTh  = (ushort*)(ws + OFF_HTH);
    ushort* hrTh = (ushort*)(ws + OFF_HRTH);
    int* bar     = (int*)(ws + OFF_BAR);
    // W-fragments alias the sproj region (dead until k_proj, which runs after recurrence)
    ushort* WzFH = (ushort*)(ws + OFF_SP);
    ushort* WzFL = WzFH + 98304;
    ushort* WhFH = WzFL + 98304;
    ushort* WhFL = WhFH + 49152;
    float* out   = (float*)d_out;

    hipMemsetAsync(deg, 0, 512 * sizeof(float), stream);
    hipMemsetAsync(L1d, 0, (size_t)Nn * Nn * sizeof(float), stream);
    hipMemsetAsync(h, 0, (size_t)Bn * NC * sizeof(float), stream);
    hipMemsetAsync(hTh, 0, 262144 * sizeof(ushort), stream);
    hipMemsetAsync(bar, 0, 4096 * sizeof(int), stream);

    k_deg<<<64, 256, 0, stream>>>(ew, esrc, deg);
    k_dinv<<<2, 256, 0, stream>>>(deg, dinv);
    k_nwdense<<<64, 256, 0, stream>>>(ew, esrc, edst, dinv, L1d);
    k_l2<<<64, 1024, 0, stream>>>(L1d, L2d);
    k_lfrag<<<2048, 256, 0, stream>>>(L1d, L2d, AfH, AfL);
    k_repack<<<(156032 + 255) / 256, 256, 0, stream>>>(Wx, bx, Wh, bh, W1,
                                                       WzrC, WhC, bzr, bht, W1cat);
    k_wfrag<<<(147456 + 255) / 256, 256, 0, stream>>>(WzrC, WhC, WzFH, WzFL, WhFH, WhFL);

    // T1x/T2x via MFMA — 1024 blocks (4 waves/SIMD)
    k_lxm<<<1024, 256, 0, stream>>>(AfH, AfL, x, T1x, T2x);

    // full recurrence in one persistent kernel: 256 blocks = 1/CU, plain launch
    k_recur<<<256, 256, 0, stream>>>(x, T1x, T2x, AfH, AfL, WzFH, WzFL,
                                     WhFH, WhFL, bzr, bht, h, hTh, hrTh, bar);

    k_proj<<<128, 256, 0, stream>>>(h, W1cat, b1, sproj, tproj);
    k_logits<<<Bn * 16 * 8, 256, 0, stream>>>(sproj, tproj, W2, b2, out);
}

// Round 11
// 645.159 us; speedup vs baseline: 1.5792x; 1.0551x over previous
//
#include <hip/hip_runtime.h>

typedef unsigned short ushort;
typedef unsigned long long u64;
typedef __attribute__((ext_vector_type(8))) short short8;
typedef __attribute__((ext_vector_type(4))) float f32x4;

// Problem constants
constexpr int Bn = 8, Tn = 16, Nn = 512, Cn = 64, Hn = 64, En = 16384, Ln = 2;
constexpr int NC = Nn * Cn;           // 32768
constexpr int MROWS = Bn * Nn;        // 4096

// ---------------- workspace layout (in floats) ----------------
constexpr size_t OFF_DEG  = 0;
constexpr size_t OFF_DINV = 512;
constexpr size_t OFF_L1D  = 1024;                         // 512*512
constexpr size_t OFF_L2D  = OFF_L1D + 262144;
constexpr size_t OFF_WZR  = OFF_L2D + 262144;             // 2*384*128
constexpr size_t OFF_WHT  = OFF_WZR + 2*384*128;          // 2*384*64
constexpr size_t OFF_BZR  = OFF_WHT + 2*384*64;
constexpr size_t OFF_BHT  = OFF_BZR + 256;
constexpr size_t OFF_W1C  = OFF_BHT + 128;                // 8192
constexpr size_t OFF_T1X  = OFF_W1C + 8192;               // B*T*N*C
constexpr size_t OFF_T2X  = OFF_T1X + (size_t)Bn*Tn*NC;
constexpr size_t OFF_H    = OFF_T2X + (size_t)Bn*Tn*NC;   // B*N*H
constexpr size_t OFF_Z    = OFF_H   + (size_t)Bn*NC;
constexpr size_t OFF_HR   = OFF_Z   + (size_t)Bn*NC;
constexpr size_t OFF_SP   = OFF_HR  + (size_t)Bn*NC;      // sproj; W-frags alias this
constexpr size_t OFF_TP   = OFF_SP  + (size_t)MROWS*Hn;
constexpr size_t OFF_LFH  = OFF_TP  + (size_t)MROWS*Hn;   // L-frags bf16 hi/lo
constexpr size_t OFF_LFL  = OFF_LFH + 262144;
constexpr size_t OFF_HTH  = OFF_LFL + 262144;             // transposed bf16 h (hi only)
constexpr size_t OFF_HTL  = OFF_HTH + 131072;             // (unused)
constexpr size_t OFF_HRTH = OFF_HTL + 131072;
constexpr size_t OFF_HRTL = OFF_HRTH + 131072;            // (unused)
constexpr size_t OFF_BAR  = OFF_HRTL + 131072;            // 4096 ints of flag state
constexpr size_t OFF_END  = OFF_BAR + 4096;

__device__ __forceinline__ ushort f2bf(float f) {
    unsigned u = __float_as_uint(f);
    u = u + 0x7FFF + ((u >> 16) & 1);
    return (ushort)(u >> 16);
}
__device__ __forceinline__ float bf2f(ushort h) {
    return __uint_as_float(((unsigned)h) << 16);
}
// fragment-linear LDS layout for a 16x64 bf16 A-operand panel:
// value (m,k) lives at (k>>5)*512 + ((k>>3)&3)*128 + m*8 + (k&7)
__device__ __forceinline__ int fragaddr(int m, int k) {
    return ((k >> 5) << 9) + (((k >> 3) & 3) << 7) + (m << 3) + (k & 7);
}

#define MFMA16(a, b, c) __builtin_amdgcn_mfma_f32_16x16x32_bf16((a), (b), (c), 0, 0, 0)

// ---------------- setup kernels ----------------
__global__ void k_deg(const float* __restrict__ w, const int* __restrict__ src,
                      float* __restrict__ deg) {
    int e = blockIdx.x * 256 + threadIdx.x;
    if (e < En) atomicAdd(&deg[src[e]], w[e]);
}

__global__ void k_dinv(const float* __restrict__ deg, float* __restrict__ dinv) {
    int n = blockIdx.x * 256 + threadIdx.x;
    if (n < Nn) {
        float d = deg[n];
        dinv[n] = d > 0.f ? rsqrtf(fmaxf(d, 1e-12f)) : 0.f;
    }
}

__global__ void k_nwdense(const float* __restrict__ w, const int* __restrict__ src,
                          const int* __restrict__ dst, const float* __restrict__ dinv,
                          float* __restrict__ L1d) {
    int e = blockIdx.x * 256 + threadIdx.x;
    if (e < En) {
        int s = src[e], d = dst[e];
        float nw = -w[e] * dinv[s] * dinv[d];
        atomicAdd(&L1d[d * Nn + s], nw);
    }
}

// L2 = 2*(L1@L1) - I.  64 blocks x 1024 threads (4 waves/SIMD), 2x2 per thread.
__global__ __launch_bounds__(1024) void k_l2(const float* __restrict__ A,
                                             float* __restrict__ C) {
    __shared__ float As[64][33];
    __shared__ float Bs[32][65];
    int t = threadIdx.x;
    int i0 = (blockIdx.x >> 3) * 64;
    int j0 = (blockIdx.x & 7) * 64;
    int tx = t & 31, ty = t >> 5;          // 32x32 threads, each 2x2
    float acc[2][2] = {};
    int ar = t >> 4, ac = (t & 15) * 2;    // A stage: 64 rows x 32 k
    int br = t >> 5, bc = (t & 31) * 2;    // B stage: 32 k x 64 j
    for (int kc = 0; kc < 512; kc += 32) {
        float2 a2 = *(const float2*)&A[(size_t)(i0 + ar) * 512 + kc + ac];
        float2 b2 = *(const float2*)&A[(size_t)(kc + br) * 512 + j0 + bc];
        As[ar][ac] = a2.x; As[ar][ac + 1] = a2.y;
        Bs[br][bc] = b2.x; Bs[br][bc + 1] = b2.y;
        __syncthreads();
#pragma unroll 8
        for (int kk = 0; kk < 32; kk++) {
            float a0 = As[ty * 2][kk], a1 = As[ty * 2 + 1][kk];
            float b0 = Bs[kk][tx * 2], b1 = Bs[kk][tx * 2 + 1];
            acc[0][0] += a0 * b0; acc[0][1] += a0 * b1;
            acc[1][0] += a1 * b0; acc[1][1] += a1 * b1;
        }
        __syncthreads();
    }
#pragma unroll
    for (int r = 0; r < 2; r++)
#pragma unroll
        for (int c = 0; c < 2; c++) {
            int i = i0 + ty * 2 + r, j = j0 + tx * 2 + c;
            C[(size_t)i * 512 + j] = 2.f * acc[r][c] - (i == j ? 1.f : 0.f);
        }
}

// L1/L2 -> bf16 split A-fragments; idx = ((mat*32+rb)*16 + kc)*512 + lane*8 + j
__global__ void k_lfrag(const float* __restrict__ L1, const float* __restrict__ L2,
                        ushort* __restrict__ AfH, ushort* __restrict__ AfL) {
    int idx = blockIdx.x * 256 + threadIdx.x;   // 0..524287
    int j = idx & 7;
    int lane = (idx >> 3) & 63;
    int kc = (idx >> 9) & 15;
    int rb = (idx >> 13) & 31;
    int mat = idx >> 18;
    int row = rb * 16 + (lane & 15);
    int k = kc * 32 + (lane >> 4) * 8 + j;
    float v = (mat ? L2 : L1)[(size_t)row * 512 + k];
    ushort hi = f2bf(v);
    AfH[idx] = hi;
    AfL[idx] = f2bf(v - bf2f(hi));
}

// Wzr/Wht -> bf16 split B-fragments: idx = ((l*CT + ct)*12 + kc)*512 + lane*8 + j
__global__ void k_wfrag(const float* __restrict__ WzrC, const float* __restrict__ WhC,
                        ushort* __restrict__ WzFH, ushort* __restrict__ WzFL,
                        ushort* __restrict__ WhFH, ushort* __restrict__ WhFL) {
    int idx = blockIdx.x * 256 + threadIdx.x;
    if (idx < 98304) {
        int l = idx / 49152, off = idx % 49152;
        int tile = off >> 9, r = off & 511;
        int lane = r >> 3, j = r & 7;
        int ct = tile / 12, kc = tile % 12;
        int k = kc * 32 + (lane >> 4) * 8 + j;
        int n = ct * 16 + (lane & 15);
        float v = WzrC[(size_t)l * 49152 + k * 128 + n];
        ushort hi = f2bf(v);
        WzFH[idx] = hi;
        WzFL[idx] = f2bf(v - bf2f(hi));
    } else if (idx < 147456) {
        int t2 = idx - 98304;
        int l = t2 / 24576, off = t2 % 24576;
        int tile = off >> 9, r = off & 511;
        int lane = r >> 3, j = r & 7;
        int ct = tile / 12, kc = tile % 12;
        int k = kc * 32 + (lane >> 4) * 8 + j;
        int n = ct * 16 + (lane & 15);
        float v = WhC[(size_t)l * 24576 + k * 64 + n];
        ushort hi = f2bf(v);
        WhFH[t2] = hi;
        WhFL[t2] = f2bf(v - bf2f(hi));
    }
}

// ---------------- MFMA T1x/T2x: o1 = L1@x, o2 = L2@x per slice ----------------
__global__ __launch_bounds__(256) void k_lxm(
        const ushort* __restrict__ AfH, const ushort* __restrict__ AfL,
        const float* __restrict__ in, float* __restrict__ o1, float* __restrict__ o2) {
    __shared__ ushort Bh[2][2176];   // [buf][n*34 + k] (pad 34 halves)
    __shared__ ushort Bl[2][2176];
    int slice = blockIdx.x >> 3;
    int rg = blockIdx.x & 7;
    const float* xs = in + (size_t)slice * NC;
    int tid = threadIdx.x;
    int lane = tid & 63, wav = tid >> 6;
    int quad = lane >> 4, l15 = lane & 15;
    int sn = tid & 63, skq = tid >> 6;
    int rt = rg * 4 + wav;
    size_t abA = ((size_t)rt * 16) * 512 + lane * 8;        // L1 rows
    size_t abB = ((size_t)(32 + rt) * 16) * 512 + lane * 8; // L2 rows
    f32x4 accA[4], accB[4];
#pragma unroll
    for (int n = 0; n < 4; n++) {
        accA[n] = (f32x4){0.f, 0.f, 0.f, 0.f};
        accB[n] = (f32x4){0.f, 0.f, 0.f, 0.f};
    }
    {
        short8 hi8, lo8;
#pragma unroll
        for (int i = 0; i < 8; i++) {
            float v = xs[(size_t)(skq * 8 + i) * 64 + sn];
            ushort hv = f2bf(v);
            hi8[i] = (short)hv;
            lo8[i] = (short)f2bf(v - bf2f(hv));
        }
        *(short8*)&Bh[0][sn * 34 + skq * 8] = hi8;
        *(short8*)&Bl[0][sn * 34 + skq * 8] = lo8;
    }
    __syncthreads();
#pragma unroll
    for (int kc = 0; kc < 16; kc++) {
        const int cur = kc & 1;
        float sv[8];
        if (kc < 15) {
#pragma unroll
            for (int i = 0; i < 8; i++)
                sv[i] = xs[(size_t)((kc + 1) * 32 + skq * 8 + i) * 64 + sn];
        }
        size_t o = (size_t)kc * 512;
        short8 lah = *(const short8*)&AfH[abA + o];
        short8 lal = *(const short8*)&AfL[abA + o];
        short8 lbh = *(const short8*)&AfH[abB + o];
        short8 lbl = *(const short8*)&AfL[abB + o];
#pragma unroll
        for (int nt = 0; nt < 4; nt++) {
            short8 xh = *(const short8*)&Bh[cur][(nt * 16 + l15) * 34 + quad * 8];
            short8 xl = *(const short8*)&Bl[cur][(nt * 16 + l15) * 34 + quad * 8];
            accA[nt] = MFMA16(lah, xh, accA[nt]);
            accA[nt] = MFMA16(lah, xl, accA[nt]);
            accA[nt] = MFMA16(lal, xh, accA[nt]);
            accB[nt] = MFMA16(lbh, xh, accB[nt]);
            accB[nt] = MFMA16(lbh, xl, accB[nt]);
            accB[nt] = MFMA16(lbl, xh, accB[nt]);
        }
        if (kc < 15) {
            short8 hi8, lo8;
#pragma unroll
            for (int i = 0; i < 8; i++) {
                ushort hv = f2bf(sv[i]);
                hi8[i] = (short)hv;
                lo8[i] = (short)f2bf(sv[i] - bf2f(hv));
            }
            *(short8*)&Bh[cur ^ 1][sn * 34 + skq * 8] = hi8;
            *(short8*)&Bl[cur ^ 1][sn * 34 + skq * 8] = lo8;
        }
        __syncthreads();
    }
    float* os1 = o1 + (size_t)slice * NC;
    float* os2 = o2 + (size_t)slice * NC;
#pragma unroll
    for (int nt = 0; nt < 4; nt++)
#pragma unroll
        for (int reg = 0; reg < 4; reg++) {
            size_t row = (size_t)(rt * 16 + quad * 4 + reg);
            os1[row * 64 + nt * 16 + l15] = accA[nt][reg];
            os2[row * 64 + nt * 16 + l15] = accB[nt][reg];
        }
}

// repack weights.  A-column order: [h | x | T1x | T2x | U1 | U2] so that
// k-tiles 0..7 depend only on block-local data and 8..11 on the exchanged U1/U2.
__global__ void k_repack(const float* __restrict__ Wx, const float* __restrict__ bx,
                         const float* __restrict__ Wh, const float* __restrict__ bh,
                         const float* __restrict__ W1,
                         float* __restrict__ WzrC, float* __restrict__ WhC,
                         float* __restrict__ bzr, float* __restrict__ bht,
                         float* __restrict__ W1cat) {
    int idx = blockIdx.x * 256 + threadIdx.x;
    if (idx < 98304) {
        int l = idx / 49152, r = idx % 49152;
        int k = r / 128, j = r % 128;
        int g = j >> 6, hh = j & 63;
        int kc, c; const float* s;
        if (k < 64)       { kc = 0; c = k; s = Wh; }
        else if (k < 256) { kc = (k - 64) >> 6; c = (k - 64) & 63; s = Wx; }
        else              { kc = 1 + ((k - 256) >> 6); c = (k - 256) & 63; s = Wh; }
        WzrC[idx] = s[((((size_t)(l*3 + g))*3 + kc)*64 + c)*64 + hh];
    } else if (idx < 147456) {
        int tI = idx - 98304;
        int l = tI / 24576, r = tI % 24576;
        int k = r / 64, hh = r % 64;
        int kc, c; const float* s;
        if (k < 64)       { kc = 0; c = k; s = Wh; }
        else if (k < 256) { kc = (k - 64) >> 6; c = (k - 64) & 63; s = Wx; }
        else              { kc = 1 + ((k - 256) >> 6); c = (k - 256) & 63; s = Wh; }
        WhC[tI] = s[((((size_t)(l*3 + 2))*3 + kc)*64 + c)*64 + hh];
    } else if (idx < 147712) {
        int tI = idx - 147456;
        int l = tI >> 7, j = tI & 127;
        int g = j >> 6, hh = j & 63;
        bzr[tI] = bh[(l*3 + g)*64 + hh] + bx[(l*3 + g)*64 + hh];
    } else if (idx < 147840) {
        int tI = idx - 147712;
        int l = tI >> 6, hh = tI & 63;
        bht[tI] = bh[(l*3 + 2)*64 + hh] + bx[(l*3 + 2)*64 + hh];
    } else if (idx < 156032) {
        int tI = idx - 147840;
        int c = tI >> 7, j = tI & 127;
        W1cat[tI] = (j < 64) ? W1[c*64 + j] : W1[(64 + c)*64 + (j - 64)];
    }
}

// ================= persistent recurrence kernel =================
// Round-6 proven structure + two critical-chain cuts this round:
// (a) phase A consumes the 16 payload loads in 4 groups with COUNTED
//     s_waitcnt vmcnt(12/8/4/0) (+ sched_barrier per rule #18) so the MALL
//     transfer tail overlaps the MFMAs instead of draining at vmcnt(0);
// (b) half-cell-1 epilogue split: h*r (needed by other blocks) is computed
//     and published FIRST; the z-gate sigmoid runs after arrive, off the
//     inter-block dependency ring.

__device__ __forceinline__ void wait_flags(int* gflags, int epoch) {
    if (threadIdx.x < 64) {
        bool done = threadIdx.x >= 32;
        while (!__all(done)) {
            if (!done)
                done = __hip_atomic_load(&gflags[threadIdx.x * 16],
                                         __ATOMIC_RELAXED,
                                         __HIP_MEMORY_SCOPE_AGENT) >= epoch;
            if (!__all(done)) __builtin_amdgcn_s_sleep(1);
        }
    }
    __syncthreads();
}

__device__ __forceinline__ void arrive(int* gflags, int rowblk, int epoch) {
    // inline-asm payload stores are NOT tracked by the compiler's waitcnt
    // model: drain them explicitly before the barrier, then publish the flag.
    asm volatile("s_waitcnt vmcnt(0)" ::: "memory");
    __syncthreads();
    if (threadIdx.x == 0)
        __hip_atomic_store(&gflags[rowblk * 16], epoch,
                           __ATOMIC_RELAXED, __HIP_MEMORY_SCOPE_AGENT);
}

// write S (fp32 [16][64]) as bf16 transposed [64 cols][16 rows of this block].
// 128 threads x one 16B coherent vector store (sc0 sc1 = write to MALL).
__device__ __forceinline__ void store_T_pay(ushort* dstB, const float* S,
                                            int n0, int tid) {
    if (tid < 128) {
        int c = tid >> 1, half = tid & 1;   // col 0..63, node-octet 0..1
        short8 v;
#pragma unroll
        for (int j = 0; j < 8; j++)
            v[j] = (short)f2bf(S[(half * 8 + j) * 64 + c]);
        asm volatile("global_store_dwordx4 %0, %1, off sc0 sc1"
                     :: "v"(dstB + (size_t)c * 512 + n0 + half * 8), "v"(v)
                     : "memory");
    }
}

// stage segs 1,2,3 (x, T1x, T2x) — identical for l=0/1, so once per t
__device__ __forceinline__ void stage_xsegs(
        ushort* AH, ushort* AL, const float* __restrict__ x,
        const float* __restrict__ t1x, const float* __restrict__ t2x,
        size_t xoff, int tid) {
    int p = tid * 4;
    int m = p >> 6, kb = p & 63;
    int fa = fragaddr(m, kb);
    const float* srcs[3] = { x + xoff, t1x + xoff, t2x + xoff };
    const int sidx[3] = { 1, 2, 3 };
#pragma unroll
    for (int q = 0; q < 3; q++) {
        float4 v = *(const float4*)&srcs[q][(size_t)m * 64 + kb];
        float vv[4] = { v.x, v.y, v.z, v.w };
        int base = sidx[q] * 1024 + fa;
#pragma unroll
        for (int j = 0; j < 4; j++) {
            ushort hi = f2bf(vv[j]);
            AH[base + j] = hi;
            AL[base + j] = f2bf(vv[j] - bf2f(hi));
        }
    }
}

// stage seg 0 from an LDS-resident fp32 16x64 buffer (h or hr)
__device__ __forceinline__ void stage_h_lds(ushort* AH, ushort* AL,
                                            const float* hs, int tid) {
    int p = tid * 4;
    int m = p >> 6, kb = p & 63;
    int fa = fragaddr(m, kb);
#pragma unroll
    for (int j = 0; j < 4; j++) {
        float v = hs[m * 64 + kb + j];
        ushort hi = f2bf(v);
        AH[fa + j] = hi;
        AL[fa + j] = f2bf(v - bf2f(hi));
    }
}

// phase A: U1 = L1[rows,:]@src, U2 = L2[rows,:]@src via split-bf16 MFMA.
// A-side from LDS-cached panels; B-side (transposed h/hr, bf16 hi only):
// 16 wide coherent loads issued back-to-back, consumed in 4 groups with
// counted vmcnt waits so the transfer overlaps the MFMAs.
// Writes U1 -> seg 4, U2 -> seg 5.
__device__ __forceinline__ void phase_A16_p(
        ushort* AH, ushort* AL, const ushort* LAH, const ushort* LAL,
        const ushort* __restrict__ sTh, int tid) {
    int lane = tid & 63, wav = tid >> 6;
    int quad = lane >> 4, l15 = lane & 15;
    int ab1 = lane * 8;
    int ab2 = 8192 + lane * 8;
    size_t bb = (size_t)(wav * 16 + l15) * 512 + quad * 8;
    f32x4 p1a = {0.f,0.f,0.f,0.f}, p1c = p1a, p2a = p1a, p2c = p1a;
    short8 bh[16];
#pragma unroll
    for (int s = 0; s < 16; s++) {
        asm volatile("global_load_dwordx4 %0, %1, off sc0 sc1"
                     : "=v"(bh[s]) : "v"(sTh + bb + (size_t)s * 32) : "memory");
    }
#define PA_CHUNK(KC) {                                                   \
        int o = (KC) * 512;                                              \
        short8 a1h = *(const short8*)&LAH[ab1 + o];                      \
        short8 a1l = *(const short8*)&LAL[ab1 + o];                      \
        short8 a2h = *(const short8*)&LAH[ab2 + o];                      \
        short8 a2l = *(const short8*)&LAL[ab2 + o];                      \
        p1a = MFMA16(a1h, bh[KC], p1a);                                  \
        p1c = MFMA16(a1l, bh[KC], p1c);                                  \
        p2a = MFMA16(a2h, bh[KC], p2a);                                  \
        p2c = MFMA16(a2l, bh[KC], p2c);                                  \
    }
#define PA_WAIT(VM)                                                      \
    asm volatile("s_waitcnt vmcnt(" #VM ")" ::: "memory");               \
    __builtin_amdgcn_sched_barrier(0);
    PA_WAIT(12) PA_CHUNK(0)  PA_CHUNK(1)  PA_CHUNK(2)  PA_CHUNK(3)
    PA_WAIT(8)  PA_CHUNK(4)  PA_CHUNK(5)  PA_CHUNK(6)  PA_CHUNK(7)
    PA_WAIT(4)  PA_CHUNK(8)  PA_CHUNK(9)  PA_CHUNK(10) PA_CHUNK(11)
    PA_WAIT(0)  PA_CHUNK(12) PA_CHUNK(13) PA_CHUNK(14) PA_CHUNK(15)
#undef PA_WAIT
#undef PA_CHUNK
    int colA = wav * 16 + l15;
#pragma unroll
    for (int reg = 0; reg < 4; reg++) {
        int row = quad * 4 + reg;
        float u1 = p1a[reg] + p1c[reg];
        float u2 = p2a[reg] + p2c[reg];
        ushort h1 = f2bf(u1), h2 = f2bf(u2);
        int fa1 = 4096 + fragaddr(row, colA);
        int fa2 = 5120 + fragaddr(row, colA);
        AH[fa1] = h1; AL[fa1] = f2bf(u1 - bf2f(h1));
        AH[fa2] = h2; AL[fa2] = f2bf(u2 - bf2f(h2));
    }
}

// phase B1 pre: kt 0..7 (segs h,x,T1x,T2x) — runs BEFORE the payload wait.
__device__ __forceinline__ void phase_B1_pre(
        const ushort* AH, const ushort* AL,
        const ushort* __restrict__ WFH, const ushort* __restrict__ WFL,
        f32x4* q, int tid) {
    int lane = tid & 63, wav = tid >> 6;
    int quad = lane >> 4, l15 = lane & 15;
    int abase = quad * 128 + l15 * 8;
    size_t w0 = ((size_t)wav * 12) * 512 + lane * 8;
    size_t w1 = ((size_t)(4 + wav) * 12) * 512 + lane * 8;
    short8 ah[2], al[2], w0h[4], w0l[4], w1h[4], w1l[4];
#pragma unroll
    for (int s = 0; s < 2; s++) {
        ah[s] = *(const short8*)&AH[abase + s * 512];
        al[s] = *(const short8*)&AL[abase + s * 512];
    }
#pragma unroll
    for (int s = 0; s < 4; s++) {
        size_t o = (size_t)s * 512;
        w0h[s] = *(const short8*)&WFH[w0 + o];
        w0l[s] = *(const short8*)&WFL[w0 + o];
        w1h[s] = *(const short8*)&WFH[w1 + o];
        w1l[s] = *(const short8*)&WFL[w1 + o];
    }
#pragma unroll
    for (int kt = 0; kt < 8; kt++) {
        int sa = kt & 1, sw = kt & 3;
        q[0] = MFMA16(ah[sa], w0h[sw], q[0]);
        q[1] = MFMA16(ah[sa], w0l[sw], q[1]);
        q[2] = MFMA16(al[sa], w0h[sw], q[2]);
        q[3] = MFMA16(ah[sa], w1h[sw], q[3]);
        q[4] = MFMA16(ah[sa], w1l[sw], q[4]);
        q[5] = MFMA16(al[sa], w1h[sw], q[5]);
        if (kt + 2 < 8) {
            ah[sa] = *(const short8*)&AH[abase + (kt + 2) * 512];
            al[sa] = *(const short8*)&AL[abase + (kt + 2) * 512];
        }
        if (kt + 4 < 8) {
            size_t o = (size_t)(kt + 4) * 512;
            w0h[sw] = *(const short8*)&WFH[w0 + o];
            w0l[sw] = *(const short8*)&WFL[w0 + o];
            w1h[sw] = *(const short8*)&WFH[w1 + o];
            w1l[sw] = *(const short8*)&WFL[w1 + o];
        }
    }
}

// phase B1 post: kt 8..11 (U1,U2) — after phase A; writes PRED.
__device__ __forceinline__ void phase_B1_post(
        const ushort* AH, const ushort* AL,
        const ushort* __restrict__ WFH, const ushort* __restrict__ WFL,
        f32x4* q, float* PRED, int tid) {
    int lane = tid & 63, wav = tid >> 6;
    int quad = lane >> 4, l15 = lane & 15;
    int abase = quad * 128 + l15 * 8;
    size_t w0 = ((size_t)wav * 12) * 512 + lane * 8;
    size_t w1 = ((size_t)(4 + wav) * 12) * 512 + lane * 8;
    short8 ah[4], al[4], w0h[4], w0l[4], w1h[4], w1l[4];
#pragma unroll
    for (int s = 0; s < 4; s++) {
        int o = (8 + s) * 512;
        ah[s] = *(const short8*)&AH[abase + o];
        al[s] = *(const short8*)&AL[abase + o];
        size_t wo = (size_t)(8 + s) * 512;
        w0h[s] = *(const short8*)&WFH[w0 + wo];
        w0l[s] = *(const short8*)&WFL[w0 + wo];
        w1h[s] = *(const short8*)&WFH[w1 + wo];
        w1l[s] = *(const short8*)&WFL[w1 + wo];
    }
#pragma unroll
    for (int kt = 0; kt < 4; kt++) {
        q[0] = MFMA16(ah[kt], w0h[kt], q[0]);
        q[1] = MFMA16(ah[kt], w0l[kt], q[1]);
        q[2] = MFMA16(al[kt], w0h[kt], q[2]);
        q[3] = MFMA16(ah[kt], w1h[kt], q[3]);
        q[4] = MFMA16(ah[kt], w1l[kt], q[4]);
        q[5] = MFMA16(al[kt], w1h[kt], q[5]);
    }
#pragma unroll
    for (int reg = 0; reg < 4; reg++) {
        int row = quad * 4 + reg;
        PRED[row * 128 + wav * 16 + l15] = q[0][reg] + q[1][reg] + q[2][reg];
        PRED[row * 128 + 64 + wav * 16 + l15] = q[3][reg] + q[4][reg] + q[5][reg];
    }
}

// phase B2 pre/post: ht[16][64] = A[16][384] @ Wht
__device__ __forceinline__ void phase_B2_pre(
        const ushort* AH, const ushort* AL,
        const ushort* __restrict__ WFH, const ushort* __restrict__ WFL,
        f32x4* q, int tid) {
    int lane = tid & 63, wav = tid >> 6;
    int quad = lane >> 4, l15 = lane & 15;
    int abase = quad * 128 + l15 * 8;
    size_t w0 = ((size_t)wav * 12) * 512 + lane * 8;
    short8 ah[2], al[2], wh[4], wl[4];
#pragma unroll
    for (int s = 0; s < 2; s++) {
        ah[s] = *(const short8*)&AH[abase + s * 512];
        al[s] = *(const short8*)&AL[abase + s * 512];
    }
#pragma unroll
    for (int s = 0; s < 4; s++) {
        wh[s] = *(const short8*)&WFH[w0 + (size_t)s * 512];
        wl[s] = *(const short8*)&WFL[w0 + (size_t)s * 512];
    }
#pragma unroll
    for (int kt = 0; kt < 8; kt++) {
        int sa = kt & 1, sw = kt & 3;
        q[0] = MFMA16(ah[sa], wh[sw], q[0]);
        q[1] = MFMA16(ah[sa], wl[sw], q[1]);
        q[2] = MFMA16(al[sa], wh[sw], q[2]);
        if (kt + 2 < 8) {
            ah[sa] = *(const short8*)&AH[abase + (kt + 2) * 512];
            al[sa] = *(const short8*)&AL[abase + (kt + 2) * 512];
        }
        if (kt + 4 < 8) {
            size_t o = (size_t)(kt + 4) * 512;
            wh[sw] = *(const short8*)&WFH[w0 + o];
            wl[sw] = *(const short8*)&WFL[w0 + o];
        }
    }
}

__device__ __forceinline__ void phase_B2_post(
        const ushort* AH, const ushort* AL,
        const ushort* __restrict__ WFH, const ushort* __restrict__ WFL,
        f32x4* q, float* PRED, int tid) {
    int lane = tid & 63, wav = tid >> 6;
    int quad = lane >> 4, l15 = lane & 15;
    int abase = quad * 128 + l15 * 8;
    size_t w0 = ((size_t)wav * 12) * 512 + lane * 8;
    short8 ah[4], al[4], wh[4], wl[4];
#pragma unroll
    for (int s = 0; s < 4; s++) {
        int o = (8 + s) * 512;
        ah[s] = *(const short8*)&AH[abase + o];
        al[s] = *(const short8*)&AL[abase + o];
        size_t wo = (size_t)(8 + s) * 512;
        wh[s] = *(const short8*)&WFH[w0 + wo];
        wl[s] = *(const short8*)&WFL[w0 + wo];
    }
#pragma unroll
    for (int kt = 0; kt < 4; kt++) {
        q[0] = MFMA16(ah[kt], wh[kt], q[0]);
        q[1] = MFMA16(ah[kt], wl[kt], q[1]);
        q[2] = MFMA16(al[kt], wh[kt], q[2]);
    }
#pragma unroll
    for (int reg = 0; reg < 4; reg++)
        PRED[(quad * 4 + reg) * 64 + wav * 16 + l15] = q[0][reg] + q[1][reg] + q[2][reg];
}

__global__ __launch_bounds__(256) void k_recur(
        const float* __restrict__ x, const float* __restrict__ t1x,
        const float* __restrict__ t2x,
        const ushort* __restrict__ AfH, const ushort* __restrict__ AfL,
        const ushort* __restrict__ WzFH, const ushort* __restrict__ WzFL,
        const ushort* __restrict__ WhFH, const ushort* __restrict__ WhFL,
        const float* __restrict__ bzr, const float* __restrict__ bht,
        float* __restrict__ h, ushort* __restrict__ hTh,
        ushort* __restrict__ hrTh, int* __restrict__ bar) {
    __shared__ __attribute__((aligned(16))) ushort AH[6144];    // 12 KB
    __shared__ __attribute__((aligned(16))) ushort AL[6144];    // 12 KB
    __shared__ __attribute__((aligned(16))) float  PRED[2048];  //  8 KB
    __shared__ __attribute__((aligned(16))) float  HS[1024];    //  4 KB (persistent h)
    __shared__ __attribute__((aligned(16))) float  ZS[1024];    //  4 KB (z gate)
    __shared__ __attribute__((aligned(16))) float  HRS[1024];   //  4 KB (h*r)
    __shared__ __attribute__((aligned(16))) ushort LAH[16384];  // 32 KB L1|L2 panels hi
    __shared__ __attribute__((aligned(16))) ushort LAL[16384];  // 32 KB lo
    int tid = threadIdx.x;
    int b = blockIdx.x & 7;          // XCD-affine grouping (perf heuristic only)
    int rowblk = blockIdx.x >> 3;
    int n0 = rowblk * 16;
    int* gflags = bar + b * 512;     // 32 slots x 16 ints (64 B apart)

    // one-time: this block's L panels -> LDS (fixed for all 64 steps); h = 0
    for (int i = tid; i < 1024; i += 256) {
        *(short8*)&LAH[i * 8] = *(const short8*)&AfH[(size_t)rowblk * 8192 + i * 8];
        *(short8*)&LAL[i * 8] = *(const short8*)&AfL[(size_t)rowblk * 8192 + i * 8];
        *(short8*)&LAH[8192 + i * 8] = *(const short8*)&AfH[(size_t)(32 + rowblk) * 8192 + i * 8];
        *(short8*)&LAL[8192 + i * 8] = *(const short8*)&AfL[(size_t)(32 + rowblk) * 8192 + i * 8];
    }
    for (int i = tid; i < 1024; i += 256) HS[i] = 0.f;
    __syncthreads();

    ushort* hThB = hTh + (size_t)b * 32768;
    ushort* hrThB = hrTh + (size_t)b * 32768;
    int ep = 0;
#pragma unroll 1
    for (int t = 0; t < Tn; t++) {
        size_t xoff = ((size_t)(b * Tn + t) * Nn + n0) * 64;
        stage_xsegs(AH, AL, x, t1x, t2x, xoff, tid);   // segs 1..3, shared by l=0/1
#pragma unroll 1
        for (int l = 0; l < Ln; l++) {
            const ushort* WzH = WzFH + (size_t)l * 49152;
            const ushort* WzL = WzFL + (size_t)l * 49152;
            const ushort* WtH = WhFH + (size_t)l * 24576;
            const ushort* WtL = WhFL + (size_t)l * 24576;
            const float* bz = bzr + l * 128;
            const float* bt = bht + l * 64;
            // ---- half-cell 1: z,r gates; hr = h*r ----
            stage_h_lds(AH, AL, HS, tid);
            __syncthreads();
            f32x4 q[6];
#pragma unroll
            for (int i = 0; i < 6; i++) q[i] = (f32x4){0.f,0.f,0.f,0.f};
            phase_B1_pre(AH, AL, WzH, WzL, q, tid);       // local kt 0..7
            wait_flags(gflags, ep);                        // previous arrivals
            phase_A16_p(AH, AL, LAH, LAL, hThB, tid);      // payload -> U1,U2
            __syncthreads();
            phase_B1_post(AH, AL, WzH, WzL, q, PRED, tid); // kt 8..11 + write
            __syncthreads();
            // epilogue part 1 (critical): r-gate -> h*r, publish, arrive
            for (int i = tid; i < 1024; i += 256) {
                int r = i >> 6, c2 = i & 63;
                float v = PRED[r * 128 + 64 + c2] + bz[64 + c2];
                float s = 1.f / (1.f + __expf(-v));
                HRS[r * 64 + c2] = HS[r * 64 + c2] * s;
            }
            __syncthreads();
            store_T_pay(hrThB, HRS, n0, tid);
            arrive(gflags, rowblk, ep + 1);
            ep++;
            // epilogue part 2 (off-ring): z-gate
            for (int i = tid; i < 1024; i += 256) {
                int r = i >> 6, c = i & 63;
                float v = PRED[r * 128 + c] + bz[c];
                ZS[r * 64 + c] = 1.f / (1.f + __expf(-v));
            }
            // ---- half-cell 2: ht; h = z*h + (1-z)*ht ----
            stage_h_lds(AH, AL, HRS, tid);
            __syncthreads();
            f32x4 r3[3];
#pragma unroll
            for (int i = 0; i < 3; i++) r3[i] = (f32x4){0.f,0.f,0.f,0.f};
            phase_B2_pre(AH, AL, WtH, WtL, r3, tid);
            wait_flags(gflags, ep);
            phase_A16_p(AH, AL, LAH, LAL, hrThB, tid);
            __syncthreads();
            phase_B2_post(AH, AL, WtH, WtL, r3, PRED, tid);
            __syncthreads();
            for (int i = tid; i < 1024; i += 256) {
                int c = i & 63;
                float v = PRED[i] + bt[c];
                // fast tanh (NaN-safe)
                float av = fabsf(v);
                float e2 = __expf(-2.f * av);
                float m = (1.f - e2) / (1.f + e2);
                float htv = v < 0.f ? -m : m;
                float zz = ZS[i], hold = HS[i];
                float hn = zz * hold + (1.f - zz) * htv;
                HS[i] = hn;
                if (t == Tn - 1 && l == Ln - 1)
                    h[((size_t)(b * Nn + n0 + (i >> 6))) * 64 + c] = hn;
            }
            __syncthreads();
            store_T_pay(hThB, HS, n0, tid);
            arrive(gflags, rowblk, ep + 1);
            ep++;
        }
    }
}

// ---------------- projections ----------------
__global__ __launch_bounds__(256) void k_proj(
        const float* __restrict__ h, const float* __restrict__ W1cat,
        const float* __restrict__ b1,
        float* __restrict__ sproj, float* __restrict__ tproj) {
    __shared__ float As[16][33];
    __shared__ float Ws[16 * 128];
    int tid = threadIdx.x;
    int row0 = blockIdx.x * 32;
    const float* hp = h + (size_t)row0 * 64;
    float acc[2][8] = {};
    int tx = tid & 15, ty = tid >> 4;
    int lr = tid >> 3;
    int lk = (tid & 7) * 2;
    int wk = tid >> 4;
    int wc = (tid & 15) * 8;
    for (int kt = 0; kt < 4; kt++) {
        int c0 = kt * 16;
        float2 a2 = *(const float2*)&hp[lr * 64 + c0 + lk];
        const float4* wsrc = (const float4*)&W1cat[(size_t)(kt * 16 + wk) * 128 + wc];
        float4 w0 = wsrc[0], w1 = wsrc[1];
        As[lk][lr] = a2.x;
        As[lk + 1][lr] = a2.y;
        *(float4*)&Ws[wk * 128 + wc] = w0;
        *(float4*)&Ws[wk * 128 + wc + 4] = w1;
        __syncthreads();
#pragma unroll
        for (int kk = 0; kk < 16; kk++) {
            float a0 = As[kk][ty * 2 + 0];
            float a1 = As[kk][ty * 2 + 1];
            float4 p0 = *(const float4*)&Ws[kk * 128 + tx * 8];
            float4 p1 = *(const float4*)&Ws[kk * 128 + tx * 8 + 4];
            float w[8] = { p0.x, p0.y, p0.z, p0.w, p1.x, p1.y, p1.z, p1.w };
#pragma unroll
            for (int cc = 0; cc < 8; cc++) {
                acc[0][cc] += a0 * w[cc];
                acc[1][cc] += a1 * w[cc];
            }
        }
        __syncthreads();
    }
#pragma unroll
    for (int rr = 0; rr < 2; rr++) {
        int row = row0 + ty * 2 + rr;
#pragma unroll
        for (int cc = 0; cc < 8; cc++) {
            int col = tx * 8 + cc;
            float v = acc[rr][cc];
            if (col < 64) sproj[(size_t)row * 64 + col] = v + b1[col];
            else tproj[(size_t)row * 64 + (col - 64)] = v;
        }
    }
}

// ---------------- logits ----------------
__global__ __launch_bounds__(256) void k_logits(
        const float* __restrict__ sproj, const float* __restrict__ tproj,
        const float* __restrict__ W2, const float* __restrict__ b2,
        float* __restrict__ out) {
    __shared__ float sp[32 * 64];
    __shared__ float tp[64 * 65];
    __shared__ float w2s[64];
    int tid = threadIdx.x;
    int bb = blockIdx.x >> 7;
    int st = (blockIdx.x >> 3) & 15;
    int tt = blockIdx.x & 7;
    const float* spg = sproj + ((size_t)bb * Nn + st * 32) * 64;
    const float* tpg = tproj + ((size_t)bb * Nn + tt * 64) * 64;
    for (int i = tid; i < 2048; i += 256) sp[i] = spg[i];
    for (int i = tid; i < 4096; i += 256) {
        int tl = i >> 6, hh = i & 63;
        tp[tl * 65 + hh] = tpg[i];
    }
    if (tid < 64) w2s[tid] = W2[tid];
    __syncthreads();
    float bias = *b2;
    int tl = tid & 63, sg = tid >> 6;
    for (int si = 0; si < 8; si++) {
        int s = sg * 8 + si;
        float acc = bias;
#pragma unroll 8
        for (int hh = 0; hh < 64; hh++) {
            float v = sp[s * 64 + hh] + tp[tl * 65 + hh];
            acc += fmaxf(v, 0.f) * w2s[hh];
        }
        out[(size_t)bb * Nn * Nn + (size_t)(st * 32 + s) * Nn + tt * 64 + tl] = acc;
    }
}

// ---------------- host ----------------
extern "C" void kernel_launch(void* const* d_in, const int* in_sizes, int n_in,
                              void* d_out, int out_size, void* d_ws, size_t ws_size,
                              hipStream_t stream) {
    const float* x  = (const float*)d_in[0];
    const float* ew = (const float*)d_in[1];
    const float* Wx = (const float*)d_in[2];
    const float* bx = (const float*)d_in[3];
    const float* Wh = (const float*)d_in[4];
    const float* bh = (const float*)d_in[5];
    const float* W1 = (const float*)d_in[6];
    const float* b1 = (const float*)d_in[7];
    const float* W2 = (const float*)d_in[8];
    const float* b2 = (const float*)d_in[9];
    const int* ei   = (const int*)d_in[10];
    const int* esrc = ei;
    const int* edst = ei + En;

    float* ws = (float*)d_ws;
    float* deg   = ws + OFF_DEG;
    float* dinv  = ws + OFF_DINV;
    float* L1d   = ws + OFF_L1D;
    float* L2d   = ws + OFF_L2D;
    float* WzrC  = ws + OFF_WZR;
    float* WhC   = ws + OFF_WHT;
    float* bzr   = ws + OFF_BZR;
    float* bht   = ws + OFF_BHT;
    float* W1cat = ws + OFF_W1C;
    float* T1x   = ws + OFF_T1X;
    float* T2x   = ws + OFF_T2X;
    float* h     = ws + OFF_H;
    float* sproj = ws + OFF_SP;
    float* tproj = ws + OFF_TP;
    ushort* AfH  = (ushort*)(ws + OFF_LFH);
    ushort* AfL  = (ushort*)(ws + OFF_LFL);
    ushort* hTh  = (ushort*)(ws + OFF_HTH);
    ushort* hrTh = (ushort*)(ws + OFF_HRTH);
    int* bar     = (int*)(ws + OFF_BAR);
    // W-fragments alias the sproj region (dead until k_proj, which runs after recurrence)
    ushort* WzFH = (ushort*)(ws + OFF_SP);
    ushort* WzFL = WzFH + 98304;
    ushort* WhFH = WzFL + 98304;
    ushort* WhFL = WhFH + 49152;
    float* out   = (float*)d_out;

    hipMemsetAsync(deg, 0, 512 * sizeof(float), stream);
    hipMemsetAsync(L1d, 0, (size_t)Nn * Nn * sizeof(float), stream);
    hipMemsetAsync(h, 0, (size_t)Bn * NC * sizeof(float), stream);
    hipMemsetAsync(hTh, 0, 262144 * sizeof(ushort), stream);
    hipMemsetAsync(bar, 0, 4096 * sizeof(int), stream);

    k_deg<<<64, 256, 0, stream>>>(ew, esrc, deg);
    k_dinv<<<2, 256, 0, stream>>>(deg, dinv);
    k_nwdense<<<64, 256, 0, stream>>>(ew, esrc, edst, dinv, L1d);
    k_l2<<<64, 1024, 0, stream>>>(L1d, L2d);
    k_lfrag<<<2048, 256, 0, stream>>>(L1d, L2d, AfH, AfL);
    k_repack<<<(156032 + 255) / 256, 256, 0, stream>>>(Wx, bx, Wh, bh, W1,
                                                       WzrC, WhC, bzr, bht, W1cat);
    k_wfrag<<<(147456 + 255) / 256, 256, 0, stream>>>(WzrC, WhC, WzFH, WzFL, WhFH, WhFL);

    // T1x/T2x via MFMA — 1024 blocks (4 waves/SIMD)
    k_lxm<<<1024, 256, 0, stream>>>(AfH, AfL, x, T1x, T2x);

    // full recurrence in one persistent kernel: 256 blocks = 1/CU, plain launch
    k_recur<<<256, 256, 0, stream>>>(x, T1x, T2x, AfH, AfL, WzFH, WzFL,
                                     WhFH, WhFL, bzr, bht, h, hTh, hrTh, bar);

    k_proj<<<128, 256, 0, stream>>>(h, W1cat, b1, sproj, tproj);
    k_logits<<<Bn * 16 * 8, 256, 0, stream>>>(sproj, tproj, W2, b2, out);
}

// Round 12
// 637.659 us; speedup vs baseline: 1.5977x; 1.0118x over previous
//
#include <hip/hip_runtime.h>

typedef unsigned short ushort;
typedef unsigned long long u64;
typedef __attribute__((ext_vector_type(8))) short short8;
typedef __attribute__((ext_vector_type(4))) float f32x4;

// Problem constants
constexpr int Bn = 8, Tn = 16, Nn = 512, Cn = 64, Hn = 64, En = 16384, Ln = 2;
constexpr int NC = Nn * Cn;           // 32768
constexpr int MROWS = Bn * Nn;        // 4096

// ---------------- workspace layout (in floats) ----------------
constexpr size_t OFF_DEG  = 0;
constexpr size_t OFF_DINV = 512;
constexpr size_t OFF_L1D  = 1024;                         // 512*512
constexpr size_t OFF_L2D  = OFF_L1D + 262144;
constexpr size_t OFF_WZR  = OFF_L2D + 262144;             // 2*384*128
constexpr size_t OFF_WHT  = OFF_WZR + 2*384*128;          // 2*384*64
constexpr size_t OFF_BZR  = OFF_WHT + 2*384*64;
constexpr size_t OFF_BHT  = OFF_BZR + 256;
constexpr size_t OFF_W1C  = OFF_BHT + 128;                // 8192
constexpr size_t OFF_T1X  = OFF_W1C + 8192;               // B*T*N*C
constexpr size_t OFF_T2X  = OFF_T1X + (size_t)Bn*Tn*NC;
constexpr size_t OFF_H    = OFF_T2X + (size_t)Bn*Tn*NC;   // B*N*H
constexpr size_t OFF_Z    = OFF_H   + (size_t)Bn*NC;
constexpr size_t OFF_HR   = OFF_Z   + (size_t)Bn*NC;
constexpr size_t OFF_SP   = OFF_HR  + (size_t)Bn*NC;      // sproj; W-frags alias this
constexpr size_t OFF_TP   = OFF_SP  + (size_t)MROWS*Hn;
constexpr size_t OFF_LFH  = OFF_TP  + (size_t)MROWS*Hn;   // L-frags bf16 hi/lo
constexpr size_t OFF_LFL  = OFF_LFH + 262144;
constexpr size_t OFF_HTH  = OFF_LFL + 262144;             // transposed bf16 h (hi only)
constexpr size_t OFF_HTL  = OFF_HTH + 131072;             // (unused)
constexpr size_t OFF_HRTH = OFF_HTL + 131072;
constexpr size_t OFF_HRTL = OFF_HRTH + 131072;            // (unused)
constexpr size_t OFF_BAR  = OFF_HRTL + 131072;            // 4096 ints of flag state
constexpr size_t OFF_END  = OFF_BAR + 4096;

__device__ __forceinline__ ushort f2bf(float f) {
    unsigned u = __float_as_uint(f);
    u = u + 0x7FFF + ((u >> 16) & 1);
    return (ushort)(u >> 16);
}
__device__ __forceinline__ float bf2f(ushort h) {
    return __uint_as_float(((unsigned)h) << 16);
}
// fragment-linear LDS layout for a 16x64 bf16 A-operand panel:
// value (m,k) lives at (k>>5)*512 + ((k>>3)&3)*128 + m*8 + (k&7)
__device__ __forceinline__ int fragaddr(int m, int k) {
    return ((k >> 5) << 9) + (((k >> 3) & 3) << 7) + (m << 3) + (k & 7);
}

#define MFMA16(a, b, c) __builtin_amdgcn_mfma_f32_16x16x32_bf16((a), (b), (c), 0, 0, 0)

// ---------------- setup kernels ----------------
__global__ void k_deg(const float* __restrict__ w, const int* __restrict__ src,
                      float* __restrict__ deg) {
    int e = blockIdx.x * 256 + threadIdx.x;
    if (e < En) atomicAdd(&deg[src[e]], w[e]);
}

__global__ void k_dinv(const float* __restrict__ deg, float* __restrict__ dinv) {
    int n = blockIdx.x * 256 + threadIdx.x;
    if (n < Nn) {
        float d = deg[n];
        dinv[n] = d > 0.f ? rsqrtf(fmaxf(d, 1e-12f)) : 0.f;
    }
}

__global__ void k_nwdense(const float* __restrict__ w, const int* __restrict__ src,
                          const int* __restrict__ dst, const float* __restrict__ dinv,
                          float* __restrict__ L1d) {
    int e = blockIdx.x * 256 + threadIdx.x;
    if (e < En) {
        int s = src[e], d = dst[e];
        float nw = -w[e] * dinv[s] * dinv[d];
        atomicAdd(&L1d[d * Nn + s], nw);
    }
}

// L2 = 2*(L1@L1) - I.  64 blocks x 1024 threads (4 waves/SIMD), 2x2 per thread.
__global__ __launch_bounds__(1024) void k_l2(const float* __restrict__ A,
                                             float* __restrict__ C) {
    __shared__ float As[64][33];
    __shared__ float Bs[32][65];
    int t = threadIdx.x;
    int i0 = (blockIdx.x >> 3) * 64;
    int j0 = (blockIdx.x & 7) * 64;
    int tx = t & 31, ty = t >> 5;          // 32x32 threads, each 2x2
    float acc[2][2] = {};
    int ar = t >> 4, ac = (t & 15) * 2;    // A stage: 64 rows x 32 k
    int br = t >> 5, bc = (t & 31) * 2;    // B stage: 32 k x 64 j
    for (int kc = 0; kc < 512; kc += 32) {
        float2 a2 = *(const float2*)&A[(size_t)(i0 + ar) * 512 + kc + ac];
        float2 b2 = *(const float2*)&A[(size_t)(kc + br) * 512 + j0 + bc];
        As[ar][ac] = a2.x; As[ar][ac + 1] = a2.y;
        Bs[br][bc] = b2.x; Bs[br][bc + 1] = b2.y;
        __syncthreads();
#pragma unroll 8
        for (int kk = 0; kk < 32; kk++) {
            float a0 = As[ty * 2][kk], a1 = As[ty * 2 + 1][kk];
            float b0 = Bs[kk][tx * 2], b1 = Bs[kk][tx * 2 + 1];
            acc[0][0] += a0 * b0; acc[0][1] += a0 * b1;
            acc[1][0] += a1 * b0; acc[1][1] += a1 * b1;
        }
        __syncthreads();
    }
#pragma unroll
    for (int r = 0; r < 2; r++)
#pragma unroll
        for (int c = 0; c < 2; c++) {
            int i = i0 + ty * 2 + r, j = j0 + tx * 2 + c;
            C[(size_t)i * 512 + j] = 2.f * acc[r][c] - (i == j ? 1.f : 0.f);
        }
}

// L1/L2 -> bf16 split A-fragments; idx = ((mat*32+rb)*16 + kc)*512 + lane*8 + j
__global__ void k_lfrag(const float* __restrict__ L1, const float* __restrict__ L2,
                        ushort* __restrict__ AfH, ushort* __restrict__ AfL) {
    int idx = blockIdx.x * 256 + threadIdx.x;   // 0..524287
    int j = idx & 7;
    int lane = (idx >> 3) & 63;
    int kc = (idx >> 9) & 15;
    int rb = (idx >> 13) & 31;
    int mat = idx >> 18;
    int row = rb * 16 + (lane & 15);
    int k = kc * 32 + (lane >> 4) * 8 + j;
    float v = (mat ? L2 : L1)[(size_t)row * 512 + k];
    ushort hi = f2bf(v);
    AfH[idx] = hi;
    AfL[idx] = f2bf(v - bf2f(hi));
}

// Wzr/Wht -> bf16 split B-fragments: idx = ((l*CT + ct)*12 + kc)*512 + lane*8 + j
__global__ void k_wfrag(const float* __restrict__ WzrC, const float* __restrict__ WhC,
                        ushort* __restrict__ WzFH, ushort* __restrict__ WzFL,
                        ushort* __restrict__ WhFH, ushort* __restrict__ WhFL) {
    int idx = blockIdx.x * 256 + threadIdx.x;
    if (idx < 98304) {
        int l = idx / 49152, off = idx % 49152;
        int tile = off >> 9, r = off & 511;
        int lane = r >> 3, j = r & 7;
        int ct = tile / 12, kc = tile % 12;
        int k = kc * 32 + (lane >> 4) * 8 + j;
        int n = ct * 16 + (lane & 15);
        float v = WzrC[(size_t)l * 49152 + k * 128 + n];
        ushort hi = f2bf(v);
        WzFH[idx] = hi;
        WzFL[idx] = f2bf(v - bf2f(hi));
    } else if (idx < 147456) {
        int t2 = idx - 98304;
        int l = t2 / 24576, off = t2 % 24576;
        int tile = off >> 9, r = off & 511;
        int lane = r >> 3, j = r & 7;
        int ct = tile / 12, kc = tile % 12;
        int k = kc * 32 + (lane >> 4) * 8 + j;
        int n = ct * 16 + (lane & 15);
        float v = WhC[(size_t)l * 24576 + k * 64 + n];
        ushort hi = f2bf(v);
        WhFH[t2] = hi;
        WhFL[t2] = f2bf(v - bf2f(hi));
    }
}

// ---------------- MFMA T1x/T2x: o1 = L1@x, o2 = L2@x per slice ----------------
__global__ __launch_bounds__(256) void k_lxm(
        const ushort* __restrict__ AfH, const ushort* __restrict__ AfL,
        const float* __restrict__ in, float* __restrict__ o1, float* __restrict__ o2) {
    __shared__ ushort Bh[2][2176];   // [buf][n*34 + k] (pad 34 halves)
    __shared__ ushort Bl[2][2176];
    int slice = blockIdx.x >> 3;
    int rg = blockIdx.x & 7;
    const float* xs = in + (size_t)slice * NC;
    int tid = threadIdx.x;
    int lane = tid & 63, wav = tid >> 6;
    int quad = lane >> 4, l15 = lane & 15;
    int sn = tid & 63, skq = tid >> 6;
    int rt = rg * 4 + wav;
    size_t abA = ((size_t)rt * 16) * 512 + lane * 8;        // L1 rows
    size_t abB = ((size_t)(32 + rt) * 16) * 512 + lane * 8; // L2 rows
    f32x4 accA[4], accB[4];
#pragma unroll
    for (int n = 0; n < 4; n++) {
        accA[n] = (f32x4){0.f, 0.f, 0.f, 0.f};
        accB[n] = (f32x4){0.f, 0.f, 0.f, 0.f};
    }
    {
        short8 hi8, lo8;
#pragma unroll
        for (int i = 0; i < 8; i++) {
            float v = xs[(size_t)(skq * 8 + i) * 64 + sn];
            ushort hv = f2bf(v);
            hi8[i] = (short)hv;
            lo8[i] = (short)f2bf(v - bf2f(hv));
        }
        *(short8*)&Bh[0][sn * 34 + skq * 8] = hi8;
        *(short8*)&Bl[0][sn * 34 + skq * 8] = lo8;
    }
    __syncthreads();
#pragma unroll
    for (int kc = 0; kc < 16; kc++) {
        const int cur = kc & 1;
        float sv[8];
        if (kc < 15) {
#pragma unroll
            for (int i = 0; i < 8; i++)
                sv[i] = xs[(size_t)((kc + 1) * 32 + skq * 8 + i) * 64 + sn];
        }
        size_t o = (size_t)kc * 512;
        short8 lah = *(const short8*)&AfH[abA + o];
        short8 lal = *(const short8*)&AfL[abA + o];
        short8 lbh = *(const short8*)&AfH[abB + o];
        short8 lbl = *(const short8*)&AfL[abB + o];
#pragma unroll
        for (int nt = 0; nt < 4; nt++) {
            short8 xh = *(const short8*)&Bh[cur][(nt * 16 + l15) * 34 + quad * 8];
            short8 xl = *(const short8*)&Bl[cur][(nt * 16 + l15) * 34 + quad * 8];
            accA[nt] = MFMA16(lah, xh, accA[nt]);
            accA[nt] = MFMA16(lah, xl, accA[nt]);
            accA[nt] = MFMA16(lal, xh, accA[nt]);
            accB[nt] = MFMA16(lbh, xh, accB[nt]);
            accB[nt] = MFMA16(lbh, xl, accB[nt]);
            accB[nt] = MFMA16(lbl, xh, accB[nt]);
        }
        if (kc < 15) {
            short8 hi8, lo8;
#pragma unroll
            for (int i = 0; i < 8; i++) {
                ushort hv = f2bf(sv[i]);
                hi8[i] = (short)hv;
                lo8[i] = (short)f2bf(sv[i] - bf2f(hv));
            }
            *(short8*)&Bh[cur ^ 1][sn * 34 + skq * 8] = hi8;
            *(short8*)&Bl[cur ^ 1][sn * 34 + skq * 8] = lo8;
        }
        __syncthreads();
    }
    float* os1 = o1 + (size_t)slice * NC;
    float* os2 = o2 + (size_t)slice * NC;
#pragma unroll
    for (int nt = 0; nt < 4; nt++)
#pragma unroll
        for (int reg = 0; reg < 4; reg++) {
            size_t row = (size_t)(rt * 16 + quad * 4 + reg);
            os1[row * 64 + nt * 16 + l15] = accA[nt][reg];
            os2[row * 64 + nt * 16 + l15] = accB[nt][reg];
        }
}

// repack weights.  A-column order: [h | x | T1x | T2x | U1 | U2] so that
// k-tiles 0..7 depend only on block-local data and 8..11 on the exchanged U1/U2.
__global__ void k_repack(const float* __restrict__ Wx, const float* __restrict__ bx,
                         const float* __restrict__ Wh, const float* __restrict__ bh,
                         const float* __restrict__ W1,
                         float* __restrict__ WzrC, float* __restrict__ WhC,
                         float* __restrict__ bzr, float* __restrict__ bht,
                         float* __restrict__ W1cat) {
    int idx = blockIdx.x * 256 + threadIdx.x;
    if (idx < 98304) {
        int l = idx / 49152, r = idx % 49152;
        int k = r / 128, j = r % 128;
        int g = j >> 6, hh = j & 63;
        int kc, c; const float* s;
        if (k < 64)       { kc = 0; c = k; s = Wh; }
        else if (k < 256) { kc = (k - 64) >> 6; c = (k - 64) & 63; s = Wx; }
        else              { kc = 1 + ((k - 256) >> 6); c = (k - 256) & 63; s = Wh; }
        WzrC[idx] = s[((((size_t)(l*3 + g))*3 + kc)*64 + c)*64 + hh];
    } else if (idx < 147456) {
        int tI = idx - 98304;
        int l = tI / 24576, r = tI % 24576;
        int k = r / 64, hh = r % 64;
        int kc, c; const float* s;
        if (k < 64)       { kc = 0; c = k; s = Wh; }
        else if (k < 256) { kc = (k - 64) >> 6; c = (k - 64) & 63; s = Wx; }
        else              { kc = 1 + ((k - 256) >> 6); c = (k - 256) & 63; s = Wh; }
        WhC[tI] = s[((((size_t)(l*3 + 2))*3 + kc)*64 + c)*64 + hh];
    } else if (idx < 147712) {
        int tI = idx - 147456;
        int l = tI >> 7, j = tI & 127;
        int g = j >> 6, hh = j & 63;
        bzr[tI] = bh[(l*3 + g)*64 + hh] + bx[(l*3 + g)*64 + hh];
    } else if (idx < 147840) {
        int tI = idx - 147712;
        int l = tI >> 6, hh = tI & 63;
        bht[tI] = bh[(l*3 + 2)*64 + hh] + bx[(l*3 + 2)*64 + hh];
    } else if (idx < 156032) {
        int tI = idx - 147840;
        int c = tI >> 7, j = tI & 127;
        W1cat[tI] = (j < 64) ? W1[c*64 + j] : W1[(64 + c)*64 + (j - 64)];
    }
}

// ================= persistent recurrence kernel =================
// Round-11 structure (k_recur 449 us) + this round: wave-0-only publish.
// vmcnt is a PER-WAVE counter, so if wave 0 issues ALL payload stores
// (2 x 16B per lane), its own s_waitcnt vmcnt(0) orders payload-before-flag
// with NO barrier and no cross-wave drain on the dependency ring:
//  - hc1: wave 0 computes r-gate sigmoid + h*r for its own column and
//    publishes, while waves 1-3 compute the z-gate concurrently (off-ring);
//  - hc2: after the h-update epilogue + one barrier, wave 0 publishes while
//    waves 1-3 run ahead into the next iteration's staging.

__device__ __forceinline__ void wait_flags(int* gflags, int epoch) {
    if (threadIdx.x < 64) {
        bool done = threadIdx.x >= 32;
        while (!__all(done)) {
            if (!done)
                done = __hip_atomic_load(&gflags[threadIdx.x * 16],
                                         __ATOMIC_RELAXED,
                                         __HIP_MEMORY_SCOPE_AGENT) >= epoch;
            if (!__all(done)) __builtin_amdgcn_s_sleep(1);
        }
    }
    __syncthreads();
}

// WAVE 0 ONLY: publish S (fp32 [16][64], LDS) as bf16 transposed
// [64 cols][16 rows at n0], 2 x 16B coherent stores per lane, then drain this
// wave's stores (vmcnt is per-wave) and post the epoch flag.
__device__ __forceinline__ void publish_pay_w0(ushort* dstB, const float* S,
                                               int n0, int c,
                                               int* gflags, int rowblk, int epoch) {
#pragma unroll
    for (int half = 0; half < 2; half++) {
        short8 v;
#pragma unroll
        for (int j = 0; j < 8; j++)
            v[j] = (short)f2bf(S[(half * 8 + j) * 64 + c]);
        asm volatile("global_store_dwordx4 %0, %1, off sc0 sc1"
                     :: "v"(dstB + (size_t)c * 512 + n0 + half * 8), "v"(v)
                     : "memory");
    }
    asm volatile("s_waitcnt vmcnt(0)" ::: "memory");
    if (c == 0)
        __hip_atomic_store(&gflags[rowblk * 16], epoch,
                           __ATOMIC_RELAXED, __HIP_MEMORY_SCOPE_AGENT);
}

// stage segs 1,2,3 (x, T1x, T2x) — identical for l=0/1, so once per t
__device__ __forceinline__ void stage_xsegs(
        ushort* AH, ushort* AL, const float* __restrict__ x,
        const float* __restrict__ t1x, const float* __restrict__ t2x,
        size_t xoff, int tid) {
    int p = tid * 4;
    int m = p >> 6, kb = p & 63;
    int fa = fragaddr(m, kb);
    const float* srcs[3] = { x + xoff, t1x + xoff, t2x + xoff };
    const int sidx[3] = { 1, 2, 3 };
#pragma unroll
    for (int q = 0; q < 3; q++) {
        float4 v = *(const float4*)&srcs[q][(size_t)m * 64 + kb];
        float vv[4] = { v.x, v.y, v.z, v.w };
        int base = sidx[q] * 1024 + fa;
#pragma unroll
        for (int j = 0; j < 4; j++) {
            ushort hi = f2bf(vv[j]);
            AH[base + j] = hi;
            AL[base + j] = f2bf(vv[j] - bf2f(hi));
        }
    }
}

// stage seg 0 from an LDS-resident fp32 16x64 buffer (h or hr)
__device__ __forceinline__ void stage_h_lds(ushort* AH, ushort* AL,
                                            const float* hs, int tid) {
    int p = tid * 4;
    int m = p >> 6, kb = p & 63;
    int fa = fragaddr(m, kb);
#pragma unroll
    for (int j = 0; j < 4; j++) {
        float v = hs[m * 64 + kb + j];
        ushort hi = f2bf(v);
        AH[fa + j] = hi;
        AL[fa + j] = f2bf(v - bf2f(hi));
    }
}

// phase A: U1 = L1[rows,:]@src, U2 = L2[rows,:]@src via split-bf16 MFMA.
// A-side from LDS-cached panels; B-side (transposed h/hr, bf16 hi only):
// 16 wide coherent loads issued back-to-back, consumed in 4 groups with
// counted vmcnt waits so the transfer overlaps the MFMAs.
// Writes U1 -> seg 4, U2 -> seg 5.
__device__ __forceinline__ void phase_A16_p(
        ushort* AH, ushort* AL, const ushort* LAH, const ushort* LAL,
        const ushort* __restrict__ sTh, int tid) {
    int lane = tid & 63, wav = tid >> 6;
    int quad = lane >> 4, l15 = lane & 15;
    int ab1 = lane * 8;
    int ab2 = 8192 + lane * 8;
    size_t bb = (size_t)(wav * 16 + l15) * 512 + quad * 8;
    f32x4 p1a = {0.f,0.f,0.f,0.f}, p1c = p1a, p2a = p1a, p2c = p1a;
    short8 bh[16];
#pragma unroll
    for (int s = 0; s < 16; s++) {
        asm volatile("global_load_dwordx4 %0, %1, off sc0 sc1"
                     : "=v"(bh[s]) : "v"(sTh + bb + (size_t)s * 32) : "memory");
    }
#define PA_CHUNK(KC) {                                                   \
        int o = (KC) * 512;                                              \
        short8 a1h = *(const short8*)&LAH[ab1 + o];                      \
        short8 a1l = *(const short8*)&LAL[ab1 + o];                      \
        short8 a2h = *(const short8*)&LAH[ab2 + o];                      \
        short8 a2l = *(const short8*)&LAL[ab2 + o];                      \
        p1a = MFMA16(a1h, bh[KC], p1a);                                  \
        p1c = MFMA16(a1l, bh[KC], p1c);                                  \
        p2a = MFMA16(a2h, bh[KC], p2a);                                  \
        p2c = MFMA16(a2l, bh[KC], p2c);                                  \
    }
#define PA_WAIT(VM)                                                      \
    asm volatile("s_waitcnt vmcnt(" #VM ")" ::: "memory");               \
    __builtin_amdgcn_sched_barrier(0);
    PA_WAIT(12) PA_CHUNK(0)  PA_CHUNK(1)  PA_CHUNK(2)  PA_CHUNK(3)
    PA_WAIT(8)  PA_CHUNK(4)  PA_CHUNK(5)  PA_CHUNK(6)  PA_CHUNK(7)
    PA_WAIT(4)  PA_CHUNK(8)  PA_CHUNK(9)  PA_CHUNK(10) PA_CHUNK(11)
    PA_WAIT(0)  PA_CHUNK(12) PA_CHUNK(13) PA_CHUNK(14) PA_CHUNK(15)
#undef PA_WAIT
#undef PA_CHUNK
    int colA = wav * 16 + l15;
#pragma unroll
    for (int reg = 0; reg < 4; reg++) {
        int row = quad * 4 + reg;
        float u1 = p1a[reg] + p1c[reg];
        float u2 = p2a[reg] + p2c[reg];
        ushort h1 = f2bf(u1), h2 = f2bf(u2);
        int fa1 = 4096 + fragaddr(row, colA);
        int fa2 = 5120 + fragaddr(row, colA);
        AH[fa1] = h1; AL[fa1] = f2bf(u1 - bf2f(h1));
        AH[fa2] = h2; AL[fa2] = f2bf(u2 - bf2f(h2));
    }
}

// phase B1 pre: kt 0..7 (segs h,x,T1x,T2x) — runs BEFORE the payload wait.
__device__ __forceinline__ void phase_B1_pre(
        const ushort* AH, const ushort* AL,
        const ushort* __restrict__ WFH, const ushort* __restrict__ WFL,
        f32x4* q, int tid) {
    int lane = tid & 63, wav = tid >> 6;
    int quad = lane >> 4, l15 = lane & 15;
    int abase = quad * 128 + l15 * 8;
    size_t w0 = ((size_t)wav * 12) * 512 + lane * 8;
    size_t w1 = ((size_t)(4 + wav) * 12) * 512 + lane * 8;
    short8 ah[2], al[2], w0h[4], w0l[4], w1h[4], w1l[4];
#pragma unroll
    for (int s = 0; s < 2; s++) {
        ah[s] = *(const short8*)&AH[abase + s * 512];
        al[s] = *(const short8*)&AL[abase + s * 512];
    }
#pragma unroll
    for (int s = 0; s < 4; s++) {
        size_t o = (size_t)s * 512;
        w0h[s] = *(const short8*)&WFH[w0 + o];
        w0l[s] = *(const short8*)&WFL[w0 + o];
        w1h[s] = *(const short8*)&WFH[w1 + o];
        w1l[s] = *(const short8*)&WFL[w1 + o];
    }
#pragma unroll
    for (int kt = 0; kt < 8; kt++) {
        int sa = kt & 1, sw = kt & 3;
        q[0] = MFMA16(ah[sa], w0h[sw], q[0]);
        q[1] = MFMA16(ah[sa], w0l[sw], q[1]);
        q[2] = MFMA16(al[sa], w0h[sw], q[2]);
        q[3] = MFMA16(ah[sa], w1h[sw], q[3]);
        q[4] = MFMA16(ah[sa], w1l[sw], q[4]);
        q[5] = MFMA16(al[sa], w1h[sw], q[5]);
        if (kt + 2 < 8) {
            ah[sa] = *(const short8*)&AH[abase + (kt + 2) * 512];
            al[sa] = *(const short8*)&AL[abase + (kt + 2) * 512];
        }
        if (kt + 4 < 8) {
            size_t o = (size_t)(kt + 4) * 512;
            w0h[sw] = *(const short8*)&WFH[w0 + o];
            w0l[sw] = *(const short8*)&WFL[w0 + o];
            w1h[sw] = *(const short8*)&WFH[w1 + o];
            w1l[sw] = *(const short8*)&WFL[w1 + o];
        }
    }
}

// phase B1 post: kt 8..11 (U1,U2) — after phase A; writes PRED.
__device__ __forceinline__ void phase_B1_post(
        const ushort* AH, const ushort* AL,
        const ushort* __restrict__ WFH, const ushort* __restrict__ WFL,
        f32x4* q, float* PRED, int tid) {
    int lane = tid & 63, wav = tid >> 6;
    int quad = lane >> 4, l15 = lane & 15;
    int abase = quad * 128 + l15 * 8;
    size_t w0 = ((size_t)wav * 12) * 512 + lane * 8;
    size_t w1 = ((size_t)(4 + wav) * 12) * 512 + lane * 8;
    short8 ah[4], al[4], w0h[4], w0l[4], w1h[4], w1l[4];
#pragma unroll
    for (int s = 0; s < 4; s++) {
        int o = (8 + s) * 512;
        ah[s] = *(const short8*)&AH[abase + o];
        al[s] = *(const short8*)&AL[abase + o];
        size_t wo = (size_t)(8 + s) * 512;
        w0h[s] = *(const short8*)&WFH[w0 + wo];
        w0l[s] = *(const short8*)&WFL[w0 + wo];
        w1h[s] = *(const short8*)&WFH[w1 + wo];
        w1l[s] = *(const short8*)&WFL[w1 + wo];
    }
#pragma unroll
    for (int kt = 0; kt < 4; kt++) {
        q[0] = MFMA16(ah[kt], w0h[kt], q[0]);
        q[1] = MFMA16(ah[kt], w0l[kt], q[1]);
        q[2] = MFMA16(al[kt], w0h[kt], q[2]);
        q[3] = MFMA16(ah[kt], w1h[kt], q[3]);
        q[4] = MFMA16(ah[kt], w1l[kt], q[4]);
        q[5] = MFMA16(al[kt], w1h[kt], q[5]);
    }
#pragma unroll
    for (int reg = 0; reg < 4; reg++) {
        int row = quad * 4 + reg;
        PRED[row * 128 + wav * 16 + l15] = q[0][reg] + q[1][reg] + q[2][reg];
        PRED[row * 128 + 64 + wav * 16 + l15] = q[3][reg] + q[4][reg] + q[5][reg];
    }
}

// phase B2 pre/post: ht[16][64] = A[16][384] @ Wht
__device__ __forceinline__ void phase_B2_pre(
        const ushort* AH, const ushort* AL,
        const ushort* __restrict__ WFH, const ushort* __restrict__ WFL,
        f32x4* q, int tid) {
    int lane = tid & 63, wav = tid >> 6;
    int quad = lane >> 4, l15 = lane & 15;
    int abase = quad * 128 + l15 * 8;
    size_t w0 = ((size_t)wav * 12) * 512 + lane * 8;
    short8 ah[2], al[2], wh[4], wl[4];
#pragma unroll
    for (int s = 0; s < 2; s++) {
        ah[s] = *(const short8*)&AH[abase + s * 512];
        al[s] = *(const short8*)&AL[abase + s * 512];
    }
#pragma unroll
    for (int s = 0; s < 4; s++) {
        wh[s] = *(const short8*)&WFH[w0 + (size_t)s * 512];
        wl[s] = *(const short8*)&WFL[w0 + (size_t)s * 512];
    }
#pragma unroll
    for (int kt = 0; kt < 8; kt++) {
        int sa = kt & 1, sw = kt & 3;
        q[0] = MFMA16(ah[sa], wh[sw], q[0]);
        q[1] = MFMA16(ah[sa], wl[sw], q[1]);
        q[2] = MFMA16(al[sa], wh[sw], q[2]);
        if (kt + 2 < 8) {
            ah[sa] = *(const short8*)&AH[abase + (kt + 2) * 512];
            al[sa] = *(const short8*)&AL[abase + (kt + 2) * 512];
        }
        if (kt + 4 < 8) {
            size_t o = (size_t)(kt + 4) * 512;
            wh[sw] = *(const short8*)&WFH[w0 + o];
            wl[sw] = *(const short8*)&WFL[w0 + o];
        }
    }
}

__device__ __forceinline__ void phase_B2_post(
        const ushort* AH, const ushort* AL,
        const ushort* __restrict__ WFH, const ushort* __restrict__ WFL,
        f32x4* q, float* PRED, int tid) {
    int lane = tid & 63, wav = tid >> 6;
    int quad = lane >> 4, l15 = lane & 15;
    int abase = quad * 128 + l15 * 8;
    size_t w0 = ((size_t)wav * 12) * 512 + lane * 8;
    short8 ah[4], al[4], wh[4], wl[4];
#pragma unroll
    for (int s = 0; s < 4; s++) {
        int o = (8 + s) * 512;
        ah[s] = *(const short8*)&AH[abase + o];
        al[s] = *(const short8*)&AL[abase + o];
        size_t wo = (size_t)(8 + s) * 512;
        wh[s] = *(const short8*)&WFH[w0 + wo];
        wl[s] = *(const short8*)&WFL[w0 + wo];
    }
#pragma unroll
    for (int kt = 0; kt < 4; kt++) {
        q[0] = MFMA16(ah[kt], wh[kt], q[0]);
        q[1] = MFMA16(ah[kt], wl[kt], q[1]);
        q[2] = MFMA16(al[kt], wh[kt], q[2]);
    }
#pragma unroll
    for (int reg = 0; reg < 4; reg++)
        PRED[(quad * 4 + reg) * 64 + wav * 16 + l15] = q[0][reg] + q[1][reg] + q[2][reg];
}

__global__ __launch_bounds__(256) void k_recur(
        const float* __restrict__ x, const float* __restrict__ t1x,
        const float* __restrict__ t2x,
        const ushort* __restrict__ AfH, const ushort* __restrict__ AfL,
        const ushort* __restrict__ WzFH, const ushort* __restrict__ WzFL,
        const ushort* __restrict__ WhFH, const ushort* __restrict__ WhFL,
        const float* __restrict__ bzr, const float* __restrict__ bht,
        float* __restrict__ h, ushort* __restrict__ hTh,
        ushort* __restrict__ hrTh, int* __restrict__ bar) {
    __shared__ __attribute__((aligned(16))) ushort AH[6144];    // 12 KB
    __shared__ __attribute__((aligned(16))) ushort AL[6144];    // 12 KB
    __shared__ __attribute__((aligned(16))) float  PRED[2048];  //  8 KB
    __shared__ __attribute__((aligned(16))) float  HS[1024];    //  4 KB (persistent h)
    __shared__ __attribute__((aligned(16))) float  ZS[1024];    //  4 KB (z gate)
    __shared__ __attribute__((aligned(16))) float  HRS[1024];   //  4 KB (h*r)
    __shared__ __attribute__((aligned(16))) ushort LAH[16384];  // 32 KB L1|L2 panels hi
    __shared__ __attribute__((aligned(16))) ushort LAL[16384];  // 32 KB lo
    int tid = threadIdx.x;
    int b = blockIdx.x & 7;          // XCD-affine grouping (perf heuristic only)
    int rowblk = blockIdx.x >> 3;
    int n0 = rowblk * 16;
    int* gflags = bar + b * 512;     // 32 slots x 16 ints (64 B apart)

    // one-time: this block's L panels -> LDS (fixed for all 64 steps); h = 0
    for (int i = tid; i < 1024; i += 256) {
        *(short8*)&LAH[i * 8] = *(const short8*)&AfH[(size_t)rowblk * 8192 + i * 8];
        *(short8*)&LAL[i * 8] = *(const short8*)&AfL[(size_t)rowblk * 8192 + i * 8];
        *(short8*)&LAH[8192 + i * 8] = *(const short8*)&AfH[(size_t)(32 + rowblk) * 8192 + i * 8];
        *(short8*)&LAL[8192 + i * 8] = *(const short8*)&AfL[(size_t)(32 + rowblk) * 8192 + i * 8];
    }
    for (int i = tid; i < 1024; i += 256) HS[i] = 0.f;
    __syncthreads();

    ushort* hThB = hTh + (size_t)b * 32768;
    ushort* hrThB = hrTh + (size_t)b * 32768;
    int ep = 0;
#pragma unroll 1
    for (int t = 0; t < Tn; t++) {
        size_t xoff = ((size_t)(b * Tn + t) * Nn + n0) * 64;
        stage_xsegs(AH, AL, x, t1x, t2x, xoff, tid);   // segs 1..3, shared by l=0/1
#pragma unroll 1
        for (int l = 0; l < Ln; l++) {
            const ushort* WzH = WzFH + (size_t)l * 49152;
            const ushort* WzL = WzFL + (size_t)l * 49152;
            const ushort* WtH = WhFH + (size_t)l * 24576;
            const ushort* WtL = WhFL + (size_t)l * 24576;
            const float* bz = bzr + l * 128;
            const float* bt = bht + l * 64;
            // ---- half-cell 1: z,r gates; hr = h*r ----
            stage_h_lds(AH, AL, HS, tid);
            __syncthreads();
            f32x4 q[6];
#pragma unroll
            for (int i = 0; i < 6; i++) q[i] = (f32x4){0.f,0.f,0.f,0.f};
            phase_B1_pre(AH, AL, WzH, WzL, q, tid);       // local kt 0..7
            wait_flags(gflags, ep);                        // previous arrivals
            phase_A16_p(AH, AL, LAH, LAL, hThB, tid);      // payload -> U1,U2
            __syncthreads();
            phase_B1_post(AH, AL, WzH, WzL, q, PRED, tid); // kt 8..11 + write
            __syncthreads();
            // wave 0: r-gate for its own column -> h*r -> publish (on-ring);
            // waves 1-3: z-gate concurrently (off-ring).
            if (tid < 64) {
                int c = tid;
                float bzv = bz[64 + c];
#pragma unroll
                for (int r = 0; r < 16; r++) {
                    float v = PRED[r * 128 + 64 + c] + bzv;
                    float s = 1.f / (1.f + __expf(-v));
                    HRS[r * 64 + c] = HS[r * 64 + c] * s;
                }
                publish_pay_w0(hrThB, HRS, n0, c, gflags, rowblk, ep + 1);
            } else {
                for (int i = tid - 64; i < 1024; i += 192) {
                    int r = i >> 6, c = i & 63;
                    float v = PRED[r * 128 + c] + bz[c];
                    ZS[r * 64 + c] = 1.f / (1.f + __expf(-v));
                }
            }
            ep++;
            __syncthreads();                 // HRS/ZS visible to all
            // ---- half-cell 2: ht; h = z*h + (1-z)*ht ----
            stage_h_lds(AH, AL, HRS, tid);
            __syncthreads();
            f32x4 r3[3];
#pragma unroll
            for (int i = 0; i < 3; i++) r3[i] = (f32x4){0.f,0.f,0.f,0.f};
            phase_B2_pre(AH, AL, WtH, WtL, r3, tid);
            wait_flags(gflags, ep);
            phase_A16_p(AH, AL, LAH, LAL, hrThB, tid);
            __syncthreads();
            phase_B2_post(AH, AL, WtH, WtL, r3, PRED, tid);
            __syncthreads();
            for (int i = tid; i < 1024; i += 256) {
                int c = i & 63;
                float v = PRED[i] + bt[c];
                // fast tanh (NaN-safe)
                float av = fabsf(v);
                float e2 = __expf(-2.f * av);
                float m = (1.f - e2) / (1.f + e2);
                float htv = v < 0.f ? -m : m;
                float zz = ZS[i], hold = HS[i];
                float hn = zz * hold + (1.f - zz) * htv;
                HS[i] = hn;
                if (t == Tn - 1 && l == Ln - 1)
                    h[((size_t)(b * Nn + n0 + (i >> 6))) * 64 + c] = hn;
            }
            __syncthreads();                 // HS stable for publish + next stage
            // wave 0 publishes h while waves 1-3 run ahead into next staging;
            // the next stage's __syncthreads re-syncs everyone.
            if (tid < 64)
                publish_pay_w0(hThB, HS, n0, tid, gflags, rowblk, ep + 1);
            ep++;
        }
    }
}

// ---------------- projections ----------------
__global__ __launch_bounds__(256) void k_proj(
        const float* __restrict__ h, const float* __restrict__ W1cat,
        const float* __restrict__ b1,
        float* __restrict__ sproj, float* __restrict__ tproj) {
    __shared__ float As[16][33];
    __shared__ float Ws[16 * 128];
    int tid = threadIdx.x;
    int row0 = blockIdx.x * 32;
    const float* hp = h + (size_t)row0 * 64;
    float acc[2][8] = {};
    int tx = tid & 15, ty = tid >> 4;
    int lr = tid >> 3;
    int lk = (tid & 7) * 2;
    int wk = tid >> 4;
    int wc = (tid & 15) * 8;
    for (int kt = 0; kt < 4; kt++) {
        int c0 = kt * 16;
        float2 a2 = *(const float2*)&hp[lr * 64 + c0 + lk];
        const float4* wsrc = (const float4*)&W1cat[(size_t)(kt * 16 + wk) * 128 + wc];
        float4 w0 = wsrc[0], w1 = wsrc[1];
        As[lk][lr] = a2.x;
        As[lk + 1][lr] = a2.y;
        *(float4*)&Ws[wk * 128 + wc] = w0;
        *(float4*)&Ws[wk * 128 + wc + 4] = w1;
        __syncthreads();
#pragma unroll
        for (int kk = 0; kk < 16; kk++) {
            float a0 = As[kk][ty * 2 + 0];
            float a1 = As[kk][ty * 2 + 1];
            float4 p0 = *(const float4*)&Ws[kk * 128 + tx * 8];
            float4 p1 = *(const float4*)&Ws[kk * 128 + tx * 8 + 4];
            float w[8] = { p0.x, p0.y, p0.z, p0.w, p1.x, p1.y, p1.z, p1.w };
#pragma unroll
            for (int cc = 0; cc < 8; cc++) {
                acc[0][cc] += a0 * w[cc];
                acc[1][cc] += a1 * w[cc];
            }
        }
        __syncthreads();
    }
#pragma unroll
    for (int rr = 0; rr < 2; rr++) {
        int row = row0 + ty * 2 + rr;
#pragma unroll
        for (int cc = 0; cc < 8; cc++) {
            int col = tx * 8 + cc;
            float v = acc[rr][cc];
            if (col < 64) sproj[(size_t)row * 64 + col] = v + b1[col];
            else tproj[(size_t)row * 64 + (col - 64)] = v;
        }
    }
}

// ---------------- logits ----------------
__global__ __launch_bounds__(256) void k_logits(
        const float* __restrict__ sproj, const float* __restrict__ tproj,
        const float* __restrict__ W2, const float* __restrict__ b2,
        float* __restrict__ out) {
    __shared__ float sp[32 * 64];
    __shared__ float tp[64 * 65];
    __shared__ float w2s[64];
    int tid = threadIdx.x;
    int bb = blockIdx.x >> 7;
    int st = (blockIdx.x >> 3) & 15;
    int tt = blockIdx.x & 7;
    const float* spg = sproj + ((size_t)bb * Nn + st * 32) * 64;
    const float* tpg = tproj + ((size_t)bb * Nn + tt * 64) * 64;
    for (int i = tid; i < 2048; i += 256) sp[i] = spg[i];
    for (int i = tid; i < 4096; i += 256) {
        int tl = i >> 6, hh = i & 63;
        tp[tl * 65 + hh] = tpg[i];
    }
    if (tid < 64) w2s[tid] = W2[tid];
    __syncthreads();
    float bias = *b2;
    int tl = tid & 63, sg = tid >> 6;
    for (int si = 0; si < 8; si++) {
        int s = sg * 8 + si;
        float acc = bias;
#pragma unroll 8
        for (int hh = 0; hh < 64; hh++) {
            float v = sp[s * 64 + hh] + tp[tl * 65 + hh];
            acc += fmaxf(v, 0.f) * w2s[hh];
        }
        out[(size_t)bb * Nn * Nn + (size_t)(st * 32 + s) * Nn + tt * 64 + tl] = acc;
    }
}

// ---------------- host ----------------
extern "C" void kernel_launch(void* const* d_in, const int* in_sizes, int n_in,
                              void* d_out, int out_size, void* d_ws, size_t ws_size,
                              hipStream_t stream) {
    const float* x  = (const float*)d_in[0];
    const float* ew = (const float*)d_in[1];
    const float* Wx = (const float*)d_in[2];
    const float* bx = (const float*)d_in[3];
    const float* Wh = (const float*)d_in[4];
    const float* bh = (const float*)d_in[5];
    const float* W1 = (const float*)d_in[6];
    const float* b1 = (const float*)d_in[7];
    const float* W2 = (const float*)d_in[8];
    const float* b2 = (const float*)d_in[9];
    const int* ei   = (const int*)d_in[10];
    const int* esrc = ei;
    const int* edst = ei + En;

    float* ws = (float*)d_ws;
    float* deg   = ws + OFF_DEG;
    float* dinv  = ws + OFF_DINV;
    float* L1d   = ws + OFF_L1D;
    float* L2d   = ws + OFF_L2D;
    float* WzrC  = ws + OFF_WZR;
    float* WhC   = ws + OFF_WHT;
    float* bzr   = ws + OFF_BZR;
    float* bht   = ws + OFF_BHT;
    float* W1cat = ws + OFF_W1C;
    float* T1x   = ws + OFF_T1X;
    float* T2x   = ws + OFF_T2X;
    float* h     = ws + OFF_H;
    float* sproj = ws + OFF_SP;
    float* tproj = ws + OFF_TP;
    ushort* AfH  = (ushort*)(ws + OFF_LFH);
    ushort* AfL  = (ushort*)(ws + OFF_LFL);
    ushort* hTh  = (ushort*)(ws + OFF_HTH);
    ushort* hrTh = (ushort*)(ws + OFF_HRTH);
    int* bar     = (int*)(ws + OFF_BAR);
    // W-fragments alias the sproj region (dead until k_proj, which runs after recurrence)
    ushort* WzFH = (ushort*)(ws + OFF_SP);
    ushort* WzFL = WzFH + 98304;
    ushort* WhFH = WzFL + 98304;
    ushort* WhFL = WhFH + 49152;
    float* out   = (float*)d_out;

    hipMemsetAsync(deg, 0, 512 * sizeof(float), stream);
    hipMemsetAsync(L1d, 0, (size_t)Nn * Nn * sizeof(float), stream);
    hipMemsetAsync(h, 0, (size_t)Bn * NC * sizeof(float), stream);
    hipMemsetAsync(hTh, 0, 262144 * sizeof(ushort), stream);
    hipMemsetAsync(bar, 0, 4096 * sizeof(int), stream);

    k_deg<<<64, 256, 0, stream>>>(ew, esrc, deg);
    k_dinv<<<2, 256, 0, stream>>>(deg, dinv);
    k_nwdense<<<64, 256, 0, stream>>>(ew, esrc, edst, dinv, L1d);
    k_l2<<<64, 1024, 0, stream>>>(L1d, L2d);
    k_lfrag<<<2048, 256, 0, stream>>>(L1d, L2d, AfH, AfL);
    k_repack<<<(156032 + 255) / 256, 256, 0, stream>>>(Wx, bx, Wh, bh, W1,
                                                       WzrC, WhC, bzr, bht, W1cat);
    k_wfrag<<<(147456 + 255) / 256, 256, 0, stream>>>(WzrC, WhC, WzFH, WzFL, WhFH, WhFL);

    // T1x/T2x via MFMA — 1024 blocks (4 waves/SIMD)
    k_lxm<<<1024, 256, 0, stream>>>(AfH, AfL, x, T1x, T2x);

    // full recurrence in one persistent kernel: 256 blocks = 1/CU, plain launch
    k_recur<<<256, 256, 0, stream>>>(x, T1x, T2x, AfH, AfL, WzFH, WzFL,
                                     WhFH, WhFL, bzr, bht, h, hTh, hrTh, bar);

    k_proj<<<128, 256, 0, stream>>>(h, W1cat, b1, sproj, tproj);
    k_logits<<<Bn * 16 * 8, 256, 0, stream>>>(sproj, tproj, W2, b2, out);
}